// Round 1
// baseline (579.402 us; speedup 1.0000x reference)
//
#include <hip/hip_runtime.h>
#include <hip/hip_bf16.h>

#define D_MODEL 1024
#define NHEADS 16
#define DK 64
#define SEQ 2048
#define BATCH 4
#define M_TOTAL (BATCH * SEQ)   // 8192
#define N_QKV (3 * D_MODEL)     // 3072

typedef __attribute__((ext_vector_type(8))) short short8;
typedef __attribute__((ext_vector_type(4))) float f32x4;

__device__ __forceinline__ f32x4 mfma16(short8 a, short8 b, f32x4 c) {
    return __builtin_amdgcn_mfma_f32_16x16x32_bf16(a, b, c, 0, 0, 0);
}

__device__ __forceinline__ unsigned short f2bf(float f) {
    union { float f; unsigned int u; } v; v.f = f;
    unsigned int r = v.u + 0x7fffu + ((v.u >> 16) & 1u);
    return (unsigned short)(r >> 16);
}

// ---------------- LayerNorm: fp32 row -> bf16 normalized row ----------------
__global__ __launch_bounds__(256) void ln_kernel(const float* __restrict__ x,
                                                 const float* __restrict__ gamma,
                                                 const float* __restrict__ beta,
                                                 unsigned short* __restrict__ xn) {
    int row = blockIdx.x;
    int tid = threadIdx.x;
    const float4* xr = (const float4*)(x + (size_t)row * D_MODEL);
    float4 v = xr[tid];
    float s  = v.x + v.y + v.z + v.w;
    float ss = v.x * v.x + v.y * v.y + v.z * v.z + v.w * v.w;
    for (int off = 32; off > 0; off >>= 1) {
        s  += __shfl_down(s, off, 64);
        ss += __shfl_down(ss, off, 64);
    }
    __shared__ float red[8];
    int wid = tid >> 6;
    if ((tid & 63) == 0) { red[wid] = s; red[wid + 4] = ss; }
    __syncthreads();
    float st  = red[0] + red[1] + red[2] + red[3];
    float sst = red[4] + red[5] + red[6] + red[7];
    float mu  = st * (1.0f / D_MODEL);
    float var = sst * (1.0f / D_MODEL) - mu * mu;
    float rs  = rsqrtf(var + 1e-5f);
    const float4* g4 = (const float4*)gamma;
    const float4* b4 = (const float4*)beta;
    float4 g = g4[tid], b = b4[tid];
    ushort4 o;
    o.x = f2bf((v.x - mu) * rs * g.x + b.x);
    o.y = f2bf((v.y - mu) * rs * g.y + b.y);
    o.z = f2bf((v.z - mu) * rs * g.z + b.z);
    o.w = f2bf((v.w - mu) * rs * g.w + b.w);
    *(ushort4*)(xn + (size_t)row * D_MODEL + tid * 4) = o;
}

// -------- transpose + cast: src fp32 [K][N] -> dst bf16 [N][K] --------
__global__ __launch_bounds__(256) void transpose_cast(const float* __restrict__ src,
                                                      unsigned short* __restrict__ dst,
                                                      int K, int N) {
    __shared__ unsigned short tile[32][33];
    int n0 = blockIdx.x * 32;
    int k0 = blockIdx.y * 32;
    int tx = threadIdx.x;   // 0..31
    int ty = threadIdx.y;   // 0..7
    for (int i = 0; i < 4; i++) {
        int k = k0 + ty + i * 8;
        tile[ty + i * 8][tx] = f2bf(src[(size_t)k * N + n0 + tx]);
    }
    __syncthreads();
    for (int i = 0; i < 4; i++) {
        int n = n0 + ty + i * 8;
        dst[(size_t)n * K + k0 + tx] = tile[tx][ty + i * 8];
    }
}

__global__ void bias_concat(const float* __restrict__ bq, const float* __restrict__ bk,
                            const float* __restrict__ bv, float* __restrict__ cat) {
    int i = blockIdx.x * 256 + threadIdx.x;
    if (i < N_QKV)
        cat[i] = (i < 1024) ? bq[i] : (i < 2048 ? bk[i - 1024] : bv[i - 2048]);
}

// -------- GEMM C[M][N] = A[M][K](bf16) x Bt[N][K](bf16)^T + bias (+residual) --------
// MODE 0: bf16 output, + bias.  MODE 1: fp32 output, + bias + residual.
template <int MODE>
__global__ __launch_bounds__(256) void gemm_bt(const unsigned short* __restrict__ A,
                                               const unsigned short* __restrict__ Bt,
                                               const float* __restrict__ bias,
                                               const float* __restrict__ residual,
                                               void* __restrict__ Cout,
                                               int M, int N, int K) {
    constexpr int BM = 64, BN = 64, BK = 32, LDSTR = 40;  // pad 8 -> ~2-way conflicts (free)
    __shared__ __align__(16) unsigned short As[BM * LDSTR];
    __shared__ __align__(16) unsigned short Bs[BN * LDSTR];
    int m0 = blockIdx.y * BM;
    int n0 = blockIdx.x * BN;
    int tid = threadIdx.x;
    int wave = tid >> 6, lane = tid & 63;
    int wm = wave >> 1, wn = wave & 1;
    f32x4 acc[2][2] = {};
    int srow = tid >> 2;           // 0..63
    int scol = (tid & 3) * 8;      // 0,8,16,24
    const unsigned short* Ag = A + (size_t)(m0 + srow) * K + scol;
    const unsigned short* Bg = Bt + (size_t)(n0 + srow) * K + scol;

    int ar = wm * 32 + (lane & 15);
    int br = wn * 32 + (lane & 15);
    int ak = (lane >> 4) * 8;

    for (int k0 = 0; k0 < K; k0 += BK) {
        __syncthreads();
        *(short8*)&As[srow * LDSTR + scol] = *(const short8*)(Ag + k0);
        *(short8*)&Bs[srow * LDSTR + scol] = *(const short8*)(Bg + k0);
        __syncthreads();
        short8 a0 = *(short8*)&As[ar * LDSTR + ak];
        short8 a1 = *(short8*)&As[(ar + 16) * LDSTR + ak];
        short8 b0 = *(short8*)&Bs[br * LDSTR + ak];
        short8 b1 = *(short8*)&Bs[(br + 16) * LDSTR + ak];
        acc[0][0] = mfma16(a0, b0, acc[0][0]);
        acc[0][1] = mfma16(a0, b1, acc[0][1]);
        acc[1][0] = mfma16(a1, b0, acc[1][0]);
        acc[1][1] = mfma16(a1, b1, acc[1][1]);
    }
    for (int ms = 0; ms < 2; ms++)
        for (int ns = 0; ns < 2; ns++)
            for (int i = 0; i < 4; i++) {
                int r = m0 + wm * 32 + ms * 16 + (lane >> 4) * 4 + i;
                int c = n0 + wn * 32 + ns * 16 + (lane & 15);
                float val = acc[ms][ns][i] + bias[c];
                if (MODE == 0) {
                    ((unsigned short*)Cout)[(size_t)r * N + c] = f2bf(val);
                } else {
                    ((float*)Cout)[(size_t)r * N + c] = val + residual[(size_t)r * N + c];
                }
            }
}

// -------- causal flash attention over packed qkv [B*S][3072] -> attn_out bf16 [B*S][1024] --------
__global__ __launch_bounds__(256) void attn_kernel(const unsigned short* __restrict__ qkv,
                                                   unsigned short* __restrict__ attn_out) {
    constexpr int KSTR = 72;    // K/Vt LDS row stride (pad 8): 144B rows, 16B-aligned
    constexpr int PSTR = 104;   // P LDS row stride (pad 40): 208B rows, 16B-aligned
    __shared__ __align__(16) unsigned short Ks[64 * KSTR];
    __shared__ __align__(16) unsigned short Vt[64 * KSTR];
    __shared__ __align__(16) unsigned short Ps[4][16 * PSTR];
    int qb = blockIdx.x;            // 0..31 (q block of 64 rows)
    int bh = blockIdx.y;            // 0..63
    int b = bh >> 4, h = bh & 15;
    int tid = threadIdx.x, wave = tid >> 6, lane = tid & 63;
    const unsigned short* qbase = qkv + (size_t)(b * SEQ) * N_QKV + h * DK;
    const unsigned short* kbase = qbase + D_MODEL;
    const unsigned short* vbase = qbase + 2 * D_MODEL;

    // Q fragments in registers (this wave's 16 q-rows x 64 d)
    int qrow = qb * 64 + wave * 16 + (lane & 15);
    int qk = (lane >> 4) * 8;
    short8 qf[2];
    qf[0] = *(const short8*)(qbase + (size_t)qrow * N_QKV + qk);
    qf[1] = *(const short8*)(qbase + (size_t)qrow * N_QKV + 32 + qk);

    f32x4 o[4] = {};
    float mrow[4], lsum[4];
    for (int i = 0; i < 4; i++) { mrow[i] = -1e30f; lsum[i] = 0.f; }

    int rloc = (lane >> 4) * 4;
    int grow = qb * 64 + wave * 16 + rloc;

    for (int j = 0; j <= qb; j++) {
        __syncthreads();
        // stage K [64][64] row-major; V transposed -> Vt[d][kv]
        for (int it = 0; it < 2; it++) {
            int c = tid + it * 256;            // 0..511
            int r = c >> 3, c8 = (c & 7) * 8;
            *(short8*)&Ks[r * KSTR + c8] =
                *(const short8*)(kbase + (size_t)(j * 64 + r) * N_QKV + c8);
            short8 vv = *(const short8*)(vbase + (size_t)(j * 64 + r) * N_QKV + c8);
            for (int i = 0; i < 8; i++)
                Vt[(c8 + i) * KSTR + r] = ((unsigned short*)&vv)[i];
        }
        __syncthreads();

        // S = Q K^T  (16 x 64 per wave)
        f32x4 s[4];
        for (int n = 0; n < 4; n++) {
            f32x4 z = {};
            short8 kb0 = *(short8*)&Ks[(n * 16 + (lane & 15)) * KSTR + qk];
            short8 kb1 = *(short8*)&Ks[(n * 16 + (lane & 15)) * KSTR + 32 + qk];
            z = mfma16(qf[0], kb0, z);
            z = mfma16(qf[1], kb1, z);
            s[n] = z;
        }
        // scale + causal mask
        bool diag = (j == qb);
        for (int n = 0; n < 4; n++)
            for (int i = 0; i < 4; i++) {
                float xv = s[n][i] * 0.125f;
                if (diag) {
                    int col = j * 64 + n * 16 + (lane & 15);
                    if (col > grow + i) xv = -1e30f;
                }
                s[n][i] = xv;
            }
        // online softmax per q-row (row i lives across 16 lanes of the half-group)
        for (int i = 0; i < 4; i++) {
            float v = fmaxf(fmaxf(s[0][i], s[1][i]), fmaxf(s[2][i], s[3][i]));
            for (int off = 1; off < 16; off <<= 1) v = fmaxf(v, __shfl_xor(v, off, 16));
            float mn = fmaxf(mrow[i], v);
            float a = __expf(mrow[i] - mn);
            mrow[i] = mn;
            float rs = 0.f;
            for (int n = 0; n < 4; n++) {
                float pe = __expf(s[n][i] - mn);
                s[n][i] = pe;
                rs += pe;
            }
            for (int off = 1; off < 16; off <<= 1) rs += __shfl_xor(rs, off, 16);
            lsum[i] = lsum[i] * a + rs;
            for (int n = 0; n < 4; n++) o[n][i] *= a;
        }
        // P -> LDS (bf16), re-read as PV A-operand
        unsigned short* pw = &Ps[wave][0];
        for (int n = 0; n < 4; n++)
            for (int i = 0; i < 4; i++)
                pw[(rloc + i) * PSTR + n * 16 + (lane & 15)] = f2bf(s[n][i]);
        short8 pa0 = *(short8*)&pw[(lane & 15) * PSTR + qk];
        short8 pa1 = *(short8*)&pw[(lane & 15) * PSTR + 32 + qk];
        for (int n = 0; n < 4; n++) {
            short8 vb0 = *(short8*)&Vt[(n * 16 + (lane & 15)) * KSTR + qk];
            short8 vb1 = *(short8*)&Vt[(n * 16 + (lane & 15)) * KSTR + 32 + qk];
            o[n] = mfma16(pa0, vb0, o[n]);
            o[n] = mfma16(pa1, vb1, o[n]);
        }
    }
    // epilogue: O /= l, store bf16
    for (int n = 0; n < 4; n++)
        for (int i = 0; i < 4; i++) {
            int r = grow + i;
            int c = h * DK + n * 16 + (lane & 15);
            attn_out[(size_t)(b * SEQ + r) * D_MODEL + c] = f2bf(o[n][i] / lsum[i]);
        }
}

extern "C" void kernel_launch(void* const* d_in, const int* in_sizes, int n_in,
                              void* d_out, int out_size, void* d_ws, size_t ws_size,
                              hipStream_t stream) {
    const float* x     = (const float*)d_in[0];
    const float* Wq    = (const float*)d_in[1];
    const float* bq    = (const float*)d_in[2];
    const float* Wk    = (const float*)d_in[3];
    const float* bk    = (const float*)d_in[4];
    const float* Wv    = (const float*)d_in[5];
    const float* bv    = (const float*)d_in[6];
    const float* Wo    = (const float*)d_in[7];
    const float* bo    = (const float*)d_in[8];
    const float* gamma = (const float*)d_in[9];
    const float* beta  = (const float*)d_in[10];
    float* out = (float*)d_out;

    char* ws = (char*)d_ws;
    // xn (16MB) is dead after the QKV GEMM; attn_out reuses it.
    unsigned short* xn     = (unsigned short*)ws;                      // 16 MB
    unsigned short* aout   = xn;                                       // alias (16 MB)
    unsigned short* wqkv_t = (unsigned short*)(ws + (16u << 20));      // 6 MB
    unsigned short* wo_t   = (unsigned short*)(ws + (22u << 20));      // 2 MB
    unsigned short* qkv    = (unsigned short*)(ws + (24u << 20));      // 48 MB
    float* biascat         = (float*)(ws + (72u << 20));               // 12 KB

    ln_kernel<<<M_TOTAL, 256, 0, stream>>>(x, gamma, beta, xn);
    dim3 tb(32, 8);
    transpose_cast<<<dim3(32, 32), tb, 0, stream>>>(Wq, wqkv_t, 1024, 1024);
    transpose_cast<<<dim3(32, 32), tb, 0, stream>>>(Wk, wqkv_t + 1024 * 1024, 1024, 1024);
    transpose_cast<<<dim3(32, 32), tb, 0, stream>>>(Wv, wqkv_t + 2 * 1024 * 1024, 1024, 1024);
    transpose_cast<<<dim3(32, 32), tb, 0, stream>>>(Wo, wo_t, 1024, 1024);
    bias_concat<<<12, 256, 0, stream>>>(bq, bk, bv, biascat);

    gemm_bt<0><<<dim3(N_QKV / 64, M_TOTAL / 64), 256, 0, stream>>>(
        xn, wqkv_t, biascat, nullptr, qkv, M_TOTAL, N_QKV, D_MODEL);

    attn_kernel<<<dim3(SEQ / 64, BATCH * NHEADS), 256, 0, stream>>>(qkv, aout);

    gemm_bt<1><<<dim3(D_MODEL / 64, M_TOTAL / 64), 256, 0, stream>>>(
        aout, wo_t, bo, x, out, M_TOTAL, D_MODEL, D_MODEL);
}

// Round 3
// 448.144 us; speedup vs baseline: 1.2929x; 1.2929x over previous
//
#include <hip/hip_runtime.h>
#include <hip/hip_bf16.h>

#define D_MODEL 1024
#define NHEADS 16
#define DK 64
#define SEQ 2048
#define BATCH 4
#define M_TOTAL (BATCH * SEQ)   // 8192
#define N_QKV (3 * D_MODEL)     // 3072

typedef __attribute__((ext_vector_type(8))) short short8;
typedef __attribute__((ext_vector_type(4))) float f32x4;

typedef const __attribute__((address_space(1))) unsigned int* gas_p;
typedef __attribute__((address_space(3))) unsigned int* las_p;

__device__ __forceinline__ void gl_lds16(const void* g, void* l) {
    __builtin_amdgcn_global_load_lds((gas_p)g, (las_p)l, 16, 0, 0);
}

__device__ __forceinline__ f32x4 mfma16(short8 a, short8 b, f32x4 c) {
    return __builtin_amdgcn_mfma_f32_16x16x32_bf16(a, b, c, 0, 0, 0);
}

__device__ __forceinline__ unsigned short f2bf(float f) {
    union { float f; unsigned int u; } v; v.f = f;
    unsigned int r = v.u + 0x7fffu + ((v.u >> 16) & 1u);
    return (unsigned short)(r >> 16);
}

// ---------------- LayerNorm: fp32 row -> bf16 normalized row ----------------
__global__ __launch_bounds__(256) void ln_kernel(const float* __restrict__ x,
                                                 const float* __restrict__ gamma,
                                                 const float* __restrict__ beta,
                                                 unsigned short* __restrict__ xn) {
    int row = blockIdx.x;
    int tid = threadIdx.x;
    const float4* xr = (const float4*)(x + (size_t)row * D_MODEL);
    float4 v = xr[tid];
    float s  = v.x + v.y + v.z + v.w;
    float ss = v.x * v.x + v.y * v.y + v.z * v.z + v.w * v.w;
    for (int off = 32; off > 0; off >>= 1) {
        s  += __shfl_down(s, off, 64);
        ss += __shfl_down(ss, off, 64);
    }
    __shared__ float red[8];
    int wid = tid >> 6;
    if ((tid & 63) == 0) { red[wid] = s; red[wid + 4] = ss; }
    __syncthreads();
    float st  = red[0] + red[1] + red[2] + red[3];
    float sst = red[4] + red[5] + red[6] + red[7];
    float mu  = st * (1.0f / D_MODEL);
    float var = sst * (1.0f / D_MODEL) - mu * mu;
    float rs  = rsqrtf(var + 1e-5f);
    const float4* g4 = (const float4*)gamma;
    const float4* b4 = (const float4*)beta;
    float4 g = g4[tid], b = b4[tid];
    ushort4 o;
    o.x = f2bf((v.x - mu) * rs * g.x + b.x);
    o.y = f2bf((v.y - mu) * rs * g.y + b.y);
    o.z = f2bf((v.z - mu) * rs * g.z + b.z);
    o.w = f2bf((v.w - mu) * rs * g.w + b.w);
    *(ushort4*)(xn + (size_t)row * D_MODEL + tid * 4) = o;
}

// -------- transpose + cast: src fp32 [K][N] -> dst bf16 [N][K] --------
__global__ __launch_bounds__(256) void transpose_cast(const float* __restrict__ src,
                                                      unsigned short* __restrict__ dst,
                                                      int K, int N) {
    __shared__ unsigned short tile[32][33];
    int n0 = blockIdx.x * 32;
    int k0 = blockIdx.y * 32;
    int tx = threadIdx.x;   // 0..31
    int ty = threadIdx.y;   // 0..7
    for (int i = 0; i < 4; i++) {
        int k = k0 + ty + i * 8;
        tile[ty + i * 8][tx] = f2bf(src[(size_t)k * N + n0 + tx]);
    }
    __syncthreads();
    for (int i = 0; i < 4; i++) {
        int n = n0 + ty + i * 8;
        dst[(size_t)n * K + k0 + tx] = tile[tx][ty + i * 8];
    }
}

__global__ void bias_concat(const float* __restrict__ bq, const float* __restrict__ bk,
                            const float* __restrict__ bv, float* __restrict__ cat) {
    int i = blockIdx.x * 256 + threadIdx.x;
    if (i < N_QKV)
        cat[i] = (i < 1024) ? bq[i] : (i < 2048 ? bk[i - 1024] : bv[i - 2048]);
}

// -------- V transpose: qkv [M][3072] V-part -> vt [bh][d][s] bf16 --------
// LDS tile [64 s][72] with chunk-of-8 XOR swizzle keyed on (s>>3) so the
// column gather on the read side spreads across banks (2-way = free).
__global__ __launch_bounds__(256) void transpose_v(const unsigned short* __restrict__ qkv,
                                                   unsigned short* __restrict__ vt) {
    __shared__ __align__(16) unsigned short tile[64 * 72];
    int s0 = blockIdx.x * 64;
    int bh = blockIdx.y;
    int b = bh >> 4, h = bh & 15;
    int tid = threadIdx.x;
    const unsigned short* src = qkv + (size_t)(b * SEQ + s0) * N_QKV + 2048 + h * DK;
    for (int it = 0; it < 2; it++) {
        int o = tid + it * 256;          // 0..511
        int sl = o >> 3, ck = o & 7;     // s-local row, chunk of 8 elems
        short8 v = *(const short8*)(src + (size_t)sl * N_QKV + ck * 8);
        *(short8*)&tile[sl * 72 + ((ck ^ ((sl >> 3) & 7)) * 8)] = v;
    }
    __syncthreads();
    unsigned short* dst = vt + (size_t)bh * DK * SEQ + s0;
    for (int it = 0; it < 2; it++) {
        int o = tid + it * 256;
        int d = o >> 3, sc = (o & 7) * 8;
        short8 v;
        for (int i = 0; i < 8; i++)
            ((unsigned short*)&v)[i] =
                tile[(sc + i) * 72 + (((d >> 3) ^ (o & 7)) * 8) + (d & 7)];
        *(short8*)(dst + (size_t)d * SEQ + sc) = v;
    }
}

// -------- GEMM (m97 structure): C[M][N] = A[M][K](bf16) x Bt[N][K](bf16)^T --------
// 128x128 tile, BK=32, 4 waves (2x2) each 64x64 = 4x4 frags, linear LDS,
// global_load_lds width-16 staging.
// MODE 0: bf16 output + bias.  MODE 1: fp32 output + bias + residual.
template <int MODE>
__global__ __launch_bounds__(256) void gemm128(const unsigned short* __restrict__ A,
                                               const unsigned short* __restrict__ Bt,
                                               const float* __restrict__ bias,
                                               const float* __restrict__ residual,
                                               void* __restrict__ Cout,
                                               int M, int N, int K) {
    constexpr int BM = 128, BN = 128, BK = 32;
    __shared__ __align__(16) unsigned short As[BM * BK];
    __shared__ __align__(16) unsigned short Bs[BN * BK];
    int m0 = blockIdx.y * BM;
    int n0 = blockIdx.x * BN;
    int tid = threadIdx.x;
    int wave = tid >> 6, lane = tid & 63;
    int wm = wave >> 1, wn = wave & 1;
    f32x4 acc[4][4] = {};

    // staging: wave w covers rows w*32..w*32+31 of each tile (2 calls x 16 rows)
    int srow = wave * 32 + (lane >> 2);             // +0 / +16 via call
    int scol = (lane & 3) * 8;                      // elems
    const unsigned short* Ag0 = A + (size_t)(m0 + srow) * K + scol;
    const unsigned short* Ag1 = A + (size_t)(m0 + srow + 16) * K + scol;
    const unsigned short* Bg0 = Bt + (size_t)(n0 + srow) * K + scol;
    const unsigned short* Bg1 = Bt + (size_t)(n0 + srow + 16) * K + scol;
    unsigned short* Al0 = &As[(wave * 32) * BK];
    unsigned short* Al1 = &As[(wave * 32 + 16) * BK];
    unsigned short* Bl0 = &Bs[(wave * 32) * BK];
    unsigned short* Bl1 = &Bs[(wave * 32 + 16) * BK];

    int fr = lane & 15;            // fragment row-in-16
    int fq = lane >> 4;            // k-quarter
    for (int k0 = 0; k0 < K; k0 += BK) {
        gl_lds16(Ag0 + k0, Al0);
        gl_lds16(Ag1 + k0, Al1);
        gl_lds16(Bg0 + k0, Bl0);
        gl_lds16(Bg1 + k0, Bl1);
        __syncthreads();
        short8 a[4], b[4];
        for (int ms = 0; ms < 4; ms++)
            a[ms] = *(short8*)&As[(wm * 64 + ms * 16 + fr) * BK + fq * 8];
        for (int ns = 0; ns < 4; ns++)
            b[ns] = *(short8*)&Bs[(wn * 64 + ns * 16 + fr) * BK + fq * 8];
        for (int ms = 0; ms < 4; ms++)
            for (int ns = 0; ns < 4; ns++)
                acc[ms][ns] = mfma16(a[ms], b[ns], acc[ms][ns]);
        __syncthreads();
    }
    for (int ms = 0; ms < 4; ms++)
        for (int ns = 0; ns < 4; ns++)
            for (int i = 0; i < 4; i++) {
                int r = m0 + wm * 64 + ms * 16 + fq * 4 + i;
                int c = n0 + wn * 64 + ns * 16 + fr;
                float val = acc[ms][ns][i] + bias[c];
                if (MODE == 0) {
                    ((unsigned short*)Cout)[(size_t)r * N + c] = f2bf(val);
                } else {
                    ((float*)Cout)[(size_t)r * N + c] = val + residual[(size_t)r * N + c];
                }
            }
}

// -------- causal flash attention; V pre-transposed in vt[bh][d][s] --------
__global__ __launch_bounds__(256) void attn_kernel(const unsigned short* __restrict__ qkv,
                                                   const unsigned short* __restrict__ vt,
                                                   unsigned short* __restrict__ attn_out) {
    constexpr int KSTR = 72;    // K/Vt LDS row stride (144B, 16B-aligned, pad 8)
    constexpr int PSTR = 104;   // P LDS row stride
    __shared__ __align__(16) unsigned short Ks[64 * KSTR];
    __shared__ __align__(16) unsigned short Vts[64 * KSTR];
    __shared__ __align__(16) unsigned short Ps[4][16 * PSTR];
    int qb = blockIdx.x;            // q block of 64 rows
    int bh = blockIdx.y;            // 0..63
    int b = bh >> 4, h = bh & 15;
    int tid = threadIdx.x, wave = tid >> 6, lane = tid & 63;
    const unsigned short* qbase = qkv + (size_t)(b * SEQ) * N_QKV + h * DK;
    const unsigned short* kbase = qbase + D_MODEL;
    const unsigned short* vtb = vt + (size_t)bh * DK * SEQ;

    int fr = lane & 15, fq = lane >> 4;
    int qrow = qb * 64 + wave * 16 + fr;
    int qk = fq * 8;
    short8 qf[2];
    qf[0] = *(const short8*)(qbase + (size_t)qrow * N_QKV + qk);
    qf[1] = *(const short8*)(qbase + (size_t)qrow * N_QKV + 32 + qk);

    f32x4 o[4] = {};
    float mrow[4], lsum[4];
    for (int i = 0; i < 4; i++) { mrow[i] = -1e30f; lsum[i] = 0.f; }

    int rloc = fq * 4;
    int grow = qb * 64 + wave * 16 + rloc;

    for (int j = 0; j <= qb; j++) {
        __syncthreads();
        // stage K rows [kv][d] and Vt rows [d][kv] — both coalesced short8
        for (int it = 0; it < 2; it++) {
            int oo = tid + it * 256;           // 0..511
            int r = oo >> 3, c8 = (oo & 7) * 8;
            *(short8*)&Ks[r * KSTR + c8] =
                *(const short8*)(kbase + (size_t)(j * 64 + r) * N_QKV + c8);
            *(short8*)&Vts[r * KSTR + c8] =
                *(const short8*)(vtb + (size_t)r * SEQ + j * 64 + c8);
        }
        __syncthreads();

        // S = Q K^T  (16 x 64 per wave)
        f32x4 s[4];
        for (int n = 0; n < 4; n++) {
            f32x4 z = {};
            short8 kb0 = *(short8*)&Ks[(n * 16 + fr) * KSTR + qk];
            short8 kb1 = *(short8*)&Ks[(n * 16 + fr) * KSTR + 32 + qk];
            z = mfma16(qf[0], kb0, z);
            z = mfma16(qf[1], kb1, z);
            s[n] = z;
        }
        bool diag = (j == qb);
        for (int n = 0; n < 4; n++)
            for (int i = 0; i < 4; i++) {
                float xv = s[n][i] * 0.125f;
                if (diag) {
                    int col = j * 64 + n * 16 + fr;
                    if (col > grow + i) xv = -1e30f;
                }
                s[n][i] = xv;
            }
        for (int i = 0; i < 4; i++) {
            float v = fmaxf(fmaxf(s[0][i], s[1][i]), fmaxf(s[2][i], s[3][i]));
            for (int off = 1; off < 16; off <<= 1) v = fmaxf(v, __shfl_xor(v, off, 16));
            float mn = fmaxf(mrow[i], v);
            float a = __expf(mrow[i] - mn);
            mrow[i] = mn;
            float rs = 0.f;
            for (int n = 0; n < 4; n++) {
                float pe = __expf(s[n][i] - mn);
                s[n][i] = pe;
                rs += pe;
            }
            for (int off = 1; off < 16; off <<= 1) rs += __shfl_xor(rs, off, 16);
            lsum[i] = lsum[i] * a + rs;
            for (int n = 0; n < 4; n++) o[n][i] *= a;
        }
        unsigned short* pw = &Ps[wave][0];
        for (int n = 0; n < 4; n++)
            for (int i = 0; i < 4; i++)
                pw[(rloc + i) * PSTR + n * 16 + fr] = f2bf(s[n][i]);
        short8 pa0 = *(short8*)&pw[fr * PSTR + qk];
        short8 pa1 = *(short8*)&pw[fr * PSTR + 32 + qk];
        for (int n = 0; n < 4; n++) {
            short8 vb0 = *(short8*)&Vts[(n * 16 + fr) * KSTR + qk];
            short8 vb1 = *(short8*)&Vts[(n * 16 + fr) * KSTR + 32 + qk];
            o[n] = mfma16(pa0, vb0, o[n]);
            o[n] = mfma16(pa1, vb1, o[n]);
        }
    }
    for (int n = 0; n < 4; n++)
        for (int i = 0; i < 4; i++) {
            int r = grow + i;
            int c = h * DK + n * 16 + fr;
            attn_out[(size_t)(b * SEQ + r) * D_MODEL + c] = f2bf(o[n][i] / lsum[i]);
        }
}

extern "C" void kernel_launch(void* const* d_in, const int* in_sizes, int n_in,
                              void* d_out, int out_size, void* d_ws, size_t ws_size,
                              hipStream_t stream) {
    const float* x     = (const float*)d_in[0];
    const float* Wq    = (const float*)d_in[1];
    const float* bq    = (const float*)d_in[2];
    const float* Wk    = (const float*)d_in[3];
    const float* bk    = (const float*)d_in[4];
    const float* Wv    = (const float*)d_in[5];
    const float* bv    = (const float*)d_in[6];
    const float* Wo    = (const float*)d_in[7];
    const float* bo    = (const float*)d_in[8];
    const float* gamma = (const float*)d_in[9];
    const float* beta  = (const float*)d_in[10];
    float* out = (float*)d_out;

    char* ws = (char*)d_ws;
    unsigned short* xn     = (unsigned short*)ws;                      // 16 MB (dead after QKV gemm)
    unsigned short* aout   = xn;                                       // alias
    unsigned short* wqkv_t = (unsigned short*)(ws + (16u << 20));      // 6 MB
    unsigned short* wo_t   = (unsigned short*)(ws + (22u << 20));      // 2 MB
    unsigned short* qkv    = (unsigned short*)(ws + (24u << 20));      // 48 MB
    unsigned short* vt     = (unsigned short*)(ws + (72u << 20));      // 16 MB
    float* biascat         = (float*)(ws + (88u << 20));               // 12 KB

    ln_kernel<<<M_TOTAL, 256, 0, stream>>>(x, gamma, beta, xn);
    dim3 tb(32, 8);
    transpose_cast<<<dim3(32, 32), tb, 0, stream>>>(Wq, wqkv_t, 1024, 1024);
    transpose_cast<<<dim3(32, 32), tb, 0, stream>>>(Wk, wqkv_t + 1024 * 1024, 1024, 1024);
    transpose_cast<<<dim3(32, 32), tb, 0, stream>>>(Wv, wqkv_t + 2 * 1024 * 1024, 1024, 1024);
    transpose_cast<<<dim3(32, 32), tb, 0, stream>>>(Wo, wo_t, 1024, 1024);
    bias_concat<<<12, 256, 0, stream>>>(bq, bk, bv, biascat);

    gemm128<0><<<dim3(N_QKV / 128, M_TOTAL / 128), 256, 0, stream>>>(
        xn, wqkv_t, biascat, nullptr, qkv, M_TOTAL, N_QKV, D_MODEL);

    transpose_v<<<dim3(SEQ / 64, BATCH * NHEADS), 256, 0, stream>>>(qkv, vt);

    attn_kernel<<<dim3(SEQ / 64, BATCH * NHEADS), 256, 0, stream>>>(qkv, vt, aout);

    gemm128<1><<<dim3(D_MODEL / 128, M_TOTAL / 128), 256, 0, stream>>>(
        aout, wo_t, bo, x, out, M_TOTAL, D_MODEL, D_MODEL);
}

// Round 4
// 390.359 us; speedup vs baseline: 1.4843x; 1.1480x over previous
//
#include <hip/hip_runtime.h>
#include <hip/hip_bf16.h>

#define D_MODEL 1024
#define NHEADS 16
#define DK 64
#define SEQ 2048
#define BATCH 4
#define M_TOTAL (BATCH * SEQ)   // 8192
#define N_QKV (3 * D_MODEL)     // 3072

typedef __attribute__((ext_vector_type(8))) short short8;
typedef __attribute__((ext_vector_type(4))) float f32x4;
typedef __attribute__((ext_vector_type(16))) float f32x16;

typedef const __attribute__((address_space(1))) unsigned int* gas_p;
typedef __attribute__((address_space(3))) unsigned int* las_p;

__device__ __forceinline__ void gl_lds16(const void* g, void* l) {
    __builtin_amdgcn_global_load_lds((gas_p)g, (las_p)l, 16, 0, 0);
}

__device__ __forceinline__ f32x4 mfma16(short8 a, short8 b, f32x4 c) {
    return __builtin_amdgcn_mfma_f32_16x16x32_bf16(a, b, c, 0, 0, 0);
}

__device__ __forceinline__ f32x16 mfma32(short8 a, short8 b, f32x16 c) {
    return __builtin_amdgcn_mfma_f32_32x32x16_bf16(a, b, c, 0, 0, 0);
}

__device__ __forceinline__ unsigned short f2bf(float f) {
    union { float f; unsigned int u; } v; v.f = f;
    unsigned int r = v.u + 0x7fffu + ((v.u >> 16) & 1u);
    return (unsigned short)(r >> 16);
}

// pack two f32 -> one u32 of 2 bf16 (RNE), hw instruction
__device__ __forceinline__ unsigned int cvtpk(float lo, float hi) {
    unsigned int r;
    asm("v_cvt_pk_bf16_f32 %0, %1, %2" : "=v"(r) : "v"(lo), "v"(hi));
    return r;
}
// swap: a' = {a.lo, b.lo}, b' = {a.hi, b.hi}  (lanes 32-63 of a <-> lanes 0-31 of b)
__device__ __forceinline__ void plswap(unsigned int& a, unsigned int& b) {
    asm("v_permlane32_swap_b32 %0, %1" : "+v"(a), "+v"(b));
}

// ---------------- LayerNorm: fp32 row -> bf16 normalized row ----------------
__global__ __launch_bounds__(256) void ln_kernel(const float* __restrict__ x,
                                                 const float* __restrict__ gamma,
                                                 const float* __restrict__ beta,
                                                 unsigned short* __restrict__ xn) {
    int row = blockIdx.x;
    int tid = threadIdx.x;
    const float4* xr = (const float4*)(x + (size_t)row * D_MODEL);
    float4 v = xr[tid];
    float s  = v.x + v.y + v.z + v.w;
    float ss = v.x * v.x + v.y * v.y + v.z * v.z + v.w * v.w;
    for (int off = 32; off > 0; off >>= 1) {
        s  += __shfl_down(s, off, 64);
        ss += __shfl_down(ss, off, 64);
    }
    __shared__ float red[8];
    int wid = tid >> 6;
    if ((tid & 63) == 0) { red[wid] = s; red[wid + 4] = ss; }
    __syncthreads();
    float st  = red[0] + red[1] + red[2] + red[3];
    float sst = red[4] + red[5] + red[6] + red[7];
    float mu  = st * (1.0f / D_MODEL);
    float var = sst * (1.0f / D_MODEL) - mu * mu;
    float rs  = rsqrtf(var + 1e-5f);
    const float4* g4 = (const float4*)gamma;
    const float4* b4 = (const float4*)beta;
    float4 g = g4[tid], b = b4[tid];
    ushort4 o;
    o.x = f2bf((v.x - mu) * rs * g.x + b.x);
    o.y = f2bf((v.y - mu) * rs * g.y + b.y);
    o.z = f2bf((v.z - mu) * rs * g.z + b.z);
    o.w = f2bf((v.w - mu) * rs * g.w + b.w);
    *(ushort4*)(xn + (size_t)row * D_MODEL + tid * 4) = o;
}

// -------- transpose + cast: src fp32 [K][N] -> dst bf16 [N][K] --------
__global__ __launch_bounds__(256) void transpose_cast(const float* __restrict__ src,
                                                      unsigned short* __restrict__ dst,
                                                      int K, int N) {
    __shared__ unsigned short tile[32][33];
    int n0 = blockIdx.x * 32;
    int k0 = blockIdx.y * 32;
    int tx = threadIdx.x;   // 0..31
    int ty = threadIdx.y;   // 0..7
    for (int i = 0; i < 4; i++) {
        int k = k0 + ty + i * 8;
        tile[ty + i * 8][tx] = f2bf(src[(size_t)k * N + n0 + tx]);
    }
    __syncthreads();
    for (int i = 0; i < 4; i++) {
        int n = n0 + ty + i * 8;
        dst[(size_t)n * K + k0 + tx] = tile[tx][ty + i * 8];
    }
}

__global__ void bias_concat(const float* __restrict__ bq, const float* __restrict__ bk,
                            const float* __restrict__ bv, float* __restrict__ cat) {
    int i = blockIdx.x * 256 + threadIdx.x;
    if (i < N_QKV)
        cat[i] = (i < 1024) ? bq[i] : (i < 2048 ? bk[i - 1024] : bv[i - 2048]);
}

// -------- V transpose: qkv [M][3072] V-part -> vt [bh][d][s] bf16 --------
__global__ __launch_bounds__(256) void transpose_v(const unsigned short* __restrict__ qkv,
                                                   unsigned short* __restrict__ vt) {
    __shared__ __align__(16) unsigned short tile[64 * 72];
    int s0 = blockIdx.x * 64;
    int bh = blockIdx.y;
    int b = bh >> 4, h = bh & 15;
    int tid = threadIdx.x;
    const unsigned short* src = qkv + (size_t)(b * SEQ + s0) * N_QKV + 2048 + h * DK;
    for (int it = 0; it < 2; it++) {
        int o = tid + it * 256;          // 0..511
        int sl = o >> 3, ck = o & 7;     // s-local row, chunk of 8 elems
        short8 v = *(const short8*)(src + (size_t)sl * N_QKV + ck * 8);
        *(short8*)&tile[sl * 72 + ((ck ^ ((sl >> 3) & 7)) * 8)] = v;
    }
    __syncthreads();
    unsigned short* dst = vt + (size_t)bh * DK * SEQ + s0;
    for (int it = 0; it < 2; it++) {
        int o = tid + it * 256;
        int d = o >> 3, sc = (o & 7) * 8;
        short8 v;
        for (int i = 0; i < 8; i++)
            ((unsigned short*)&v)[i] =
                tile[(sc + i) * 72 + (((d >> 3) ^ (o & 7)) * 8) + (d & 7)];
        *(short8*)(dst + (size_t)d * SEQ + sc) = v;
    }
}

// -------- GEMM (m97 structure): C[M][N] = A[M][K](bf16) x Bt[N][K](bf16)^T --------
template <int MODE>
__global__ __launch_bounds__(256) void gemm128(const unsigned short* __restrict__ A,
                                               const unsigned short* __restrict__ Bt,
                                               const float* __restrict__ bias,
                                               const float* __restrict__ residual,
                                               void* __restrict__ Cout,
                                               int M, int N, int K) {
    constexpr int BM = 128, BN = 128, BK = 32;
    __shared__ __align__(16) unsigned short As[BM * BK];
    __shared__ __align__(16) unsigned short Bs[BN * BK];
    int m0 = blockIdx.y * BM;
    int n0 = blockIdx.x * BN;
    int tid = threadIdx.x;
    int wave = tid >> 6, lane = tid & 63;
    int wm = wave >> 1, wn = wave & 1;
    f32x4 acc[4][4] = {};

    int srow = wave * 32 + (lane >> 2);
    int scol = (lane & 3) * 8;
    const unsigned short* Ag0 = A + (size_t)(m0 + srow) * K + scol;
    const unsigned short* Ag1 = A + (size_t)(m0 + srow + 16) * K + scol;
    const unsigned short* Bg0 = Bt + (size_t)(n0 + srow) * K + scol;
    const unsigned short* Bg1 = Bt + (size_t)(n0 + srow + 16) * K + scol;
    unsigned short* Al0 = &As[(wave * 32) * BK];
    unsigned short* Al1 = &As[(wave * 32 + 16) * BK];
    unsigned short* Bl0 = &Bs[(wave * 32) * BK];
    unsigned short* Bl1 = &Bs[(wave * 32 + 16) * BK];

    int fr = lane & 15;
    int fq = lane >> 4;
    for (int k0 = 0; k0 < K; k0 += BK) {
        gl_lds16(Ag0 + k0, Al0);
        gl_lds16(Ag1 + k0, Al1);
        gl_lds16(Bg0 + k0, Bl0);
        gl_lds16(Bg1 + k0, Bl1);
        __syncthreads();
        short8 a[4], b[4];
        for (int ms = 0; ms < 4; ms++)
            a[ms] = *(short8*)&As[(wm * 64 + ms * 16 + fr) * BK + fq * 8];
        for (int ns = 0; ns < 4; ns++)
            b[ns] = *(short8*)&Bs[(wn * 64 + ns * 16 + fr) * BK + fq * 8];
        for (int ms = 0; ms < 4; ms++)
            for (int ns = 0; ns < 4; ns++)
                acc[ms][ns] = mfma16(a[ms], b[ns], acc[ms][ns]);
        __syncthreads();
    }
    for (int ms = 0; ms < 4; ms++)
        for (int ns = 0; ns < 4; ns++)
            for (int i = 0; i < 4; i++) {
                int r = m0 + wm * 64 + ms * 16 + fq * 4 + i;
                int c = n0 + wn * 64 + ns * 16 + fr;
                float val = acc[ms][ns][i] + bias[c];
                if (MODE == 0) {
                    ((unsigned short*)Cout)[(size_t)r * N + c] = f2bf(val);
                } else {
                    ((float*)Cout)[(size_t)r * N + c] = val + residual[(size_t)r * N + c];
                }
            }
}

// -------- causal flash attention, swapped-QK^T 32x32 structure --------
// Block: 128 threads = 2 waves; wave w owns q rows qb*64+w*32+(lane&31).
// S^T = mfma(K, Q): lane holds q-col (lane&31), kv rows in regs -> in-register
// softmax; P redistributed to PV B-operand via cvt_pk + permlane32_swap (T12).
// K/V staged via global_load_lds with chunk-XOR pre-swizzled global addresses
// (m173) -> conflict-free ds_read_b128. Double-buffered, 1 barrier per tile.
__global__ __launch_bounds__(128, 4) void attn_kernel(const unsigned short* __restrict__ qkv,
                                                      const unsigned short* __restrict__ vt,
                                                      unsigned short* __restrict__ attn_out) {
    __shared__ __align__(16) unsigned short Ks[2][64 * 64];
    __shared__ __align__(16) unsigned short Vs[2][64 * 64];
    int qb = blockIdx.x;            // q strip of 64 rows
    int bh = blockIdx.y;
    int b = bh >> 4, h = bh & 15;
    int tid = threadIdx.x, w = tid >> 6, lane = tid & 63;
    int l5 = lane >> 5;             // hi half
    int q31 = lane & 31;
    int l7 = lane & 7;
    int qg = qb * 64 + w * 32 + q31;   // this lane's global q row

    const unsigned short* kbase = qkv + (size_t)(b * SEQ) * N_QKV + D_MODEL + h * DK;
    const unsigned short* vtb = vt + (size_t)bh * DK * SEQ;

    // Q B-fragments: lane q-row, k-slot s covers d = 16s + 8*l5 + {0..7}
    const unsigned short* qptr = qkv + (size_t)(b * SEQ + qg) * N_QKV + h * DK;
    short8 qf[4];
#pragma unroll
    for (int s = 0; s < 4; s++)
        qf[s] = *(const short8*)(qptr + 16 * s + 8 * l5);

    // staging constants: lane -> (row = base+lane>>3, chunk = lane&7),
    // global chunk pre-swizzled so LDS[row][c] holds global chunk c^(row&7)
    int srow = lane >> 3;                  // 0..7 within 8-row group
    int schunk = (l7 ^ srow) * 8;          // elems

    f32x16 ot0 = {}, ot1 = {};
    float mold = -1e30f, lsum = 0.f;

    // prologue: stage tile 0 into buffer 0
#pragma unroll
    for (int c = 0; c < 4; c++) {
        int rl_ = w * 32 + c * 8;
        gl_lds16(kbase + (size_t)(rl_ + srow) * N_QKV + schunk, &Ks[0][rl_ * 64]);
        gl_lds16(vtb + (size_t)(rl_ + srow) * SEQ + schunk, &Vs[0][rl_ * 64]);
    }
    __syncthreads();

    for (int j = 0; j <= qb; j++) {
        int bb = j & 1;
        // stage next tile into other buffer (overlaps with compute below)
        if (j < qb) {
#pragma unroll
            for (int c = 0; c < 4; c++) {
                int rl_ = w * 32 + c * 8;
                gl_lds16(kbase + (size_t)((j + 1) * 64 + rl_ + srow) * N_QKV + schunk,
                         &Ks[bb ^ 1][rl_ * 64]);
                gl_lds16(vtb + (size_t)(rl_ + srow) * SEQ + (j + 1) * 64 + schunk,
                         &Vs[bb ^ 1][rl_ * 64]);
            }
        }
        const unsigned short* kb = Ks[bb];
        const unsigned short* vb = Vs[bb];
        // per-lane swizzled chunk offsets for k-slot s: ((2s|l5)^(lane&7))*16B
        // S^T = K . Q^T : two 32-kv tiles, chain over 4 k-slots
        f32x16 s0 = {}, s1 = {};
#pragma unroll
        for (int s = 0; s < 4; s++) {
            int co = (((s << 1) | l5) ^ l7) * 8;
            short8 k0 = *(const short8*)&kb[(q31) * 64 + co];
            short8 k1 = *(const short8*)&kb[(32 + q31) * 64 + co];
            s0 = mfma32(k0, qf[s], s0);
            s1 = mfma32(k1, qf[s], s1);
        }
        // scale + causal mask (mask only on diagonal tile; j==qb is warp-uniform)
        const float SC = 0.125f;
        if (j == qb) {
#pragma unroll
            for (int r = 0; r < 16; r++) {
                int kv0 = j * 64 + (r & 3) + 8 * (r >> 2) + 4 * l5;
                s0[r] = (kv0 <= qg) ? s0[r] * SC : -1e30f;
                s1[r] = (kv0 + 32 <= qg) ? s1[r] * SC : -1e30f;
            }
        } else {
#pragma unroll
            for (int r = 0; r < 16; r++) { s0[r] *= SC; s1[r] *= SC; }
        }
        // in-register online softmax: row = lane's q; halves at lane^32
        float mloc = s0[0];
#pragma unroll
        for (int r = 1; r < 16; r++) mloc = fmaxf(mloc, s0[r]);
#pragma unroll
        for (int r = 0; r < 16; r++) mloc = fmaxf(mloc, s1[r]);
        mloc = fmaxf(mloc, __shfl_xor(mloc, 32));
        float mnew = fmaxf(mold, mloc);
        float aexp = __expf(mold - mnew);
        mold = mnew;
        float lloc = 0.f;
#pragma unroll
        for (int r = 0; r < 16; r++) { s0[r] = __expf(s0[r] - mnew); lloc += s0[r]; }
#pragma unroll
        for (int r = 0; r < 16; r++) { s1[r] = __expf(s1[r] - mnew); lloc += s1[r]; }
        lloc += __shfl_xor(lloc, 32);
        lsum = lsum * aexp + lloc;
#pragma unroll
        for (int r = 0; r < 16; r++) { ot0[r] *= aexp; ot1[r] *= aexp; }

        // P -> bf16 B-fragments via cvt_pk + permlane32_swap; PV accumulate
        union { unsigned int wd[4]; short8 v; } pf;
#pragma unroll
        for (int t = 0; t < 4; t++) {           // kv-slot = t  (2 per S-tile)
            int b2 = t & 1;
            unsigned int pa, pb, pc, pd;
            if (t < 2) {
                pa = cvtpk(s0[8 * b2 + 0], s0[8 * b2 + 1]);
                pb = cvtpk(s0[8 * b2 + 2], s0[8 * b2 + 3]);
                pc = cvtpk(s0[8 * b2 + 4], s0[8 * b2 + 5]);
                pd = cvtpk(s0[8 * b2 + 6], s0[8 * b2 + 7]);
            } else {
                pa = cvtpk(s1[8 * b2 + 0], s1[8 * b2 + 1]);
                pb = cvtpk(s1[8 * b2 + 2], s1[8 * b2 + 3]);
                pc = cvtpk(s1[8 * b2 + 4], s1[8 * b2 + 5]);
                pd = cvtpk(s1[8 * b2 + 6], s1[8 * b2 + 7]);
            }
            plswap(pa, pc);
            plswap(pb, pd);
            pf.wd[0] = pa; pf.wd[1] = pb; pf.wd[2] = pc; pf.wd[3] = pd;
            int co = (((t << 1) | l5) ^ l7) * 8;
            short8 v0 = *(const short8*)&vb[(q31) * 64 + co];
            short8 v1 = *(const short8*)&vb[(32 + q31) * 64 + co];
            ot0 = mfma32(v0, pf.v, ot0);
            ot1 = mfma32(v1, pf.v, ot1);
        }
        __syncthreads();   // drains this wave's staging loads, releases buffers
    }

    // epilogue: O^T[d][q] -> attn_out[q][h*64+d], divide by lsum, pack bf16
    float rl = 1.0f / lsum;
    unsigned short* ob = attn_out + (size_t)(b * SEQ + qg) * D_MODEL + h * DK + 4 * l5;
#pragma unroll
    for (int qq = 0; qq < 4; qq++) {
        uint2 val;
        val.x = cvtpk(ot0[4 * qq + 0] * rl, ot0[4 * qq + 1] * rl);
        val.y = cvtpk(ot0[4 * qq + 2] * rl, ot0[4 * qq + 3] * rl);
        *(uint2*)(ob + 8 * qq) = val;
        val.x = cvtpk(ot1[4 * qq + 0] * rl, ot1[4 * qq + 1] * rl);
        val.y = cvtpk(ot1[4 * qq + 2] * rl, ot1[4 * qq + 3] * rl);
        *(uint2*)(ob + 32 + 8 * qq) = val;
    }
}

extern "C" void kernel_launch(void* const* d_in, const int* in_sizes, int n_in,
                              void* d_out, int out_size, void* d_ws, size_t ws_size,
                              hipStream_t stream) {
    const float* x     = (const float*)d_in[0];
    const float* Wq    = (const float*)d_in[1];
    const float* bq    = (const float*)d_in[2];
    const float* Wk    = (const float*)d_in[3];
    const float* bk    = (const float*)d_in[4];
    const float* Wv    = (const float*)d_in[5];
    const float* bv    = (const float*)d_in[6];
    const float* Wo    = (const float*)d_in[7];
    const float* bo    = (const float*)d_in[8];
    const float* gamma = (const float*)d_in[9];
    const float* beta  = (const float*)d_in[10];
    float* out = (float*)d_out;

    char* ws = (char*)d_ws;
    unsigned short* xn     = (unsigned short*)ws;                      // 16 MB (dead after QKV gemm)
    unsigned short* aout   = xn;                                       // alias
    unsigned short* wqkv_t = (unsigned short*)(ws + (16u << 20));      // 6 MB
    unsigned short* wo_t   = (unsigned short*)(ws + (22u << 20));      // 2 MB
    unsigned short* qkv    = (unsigned short*)(ws + (24u << 20));      // 48 MB
    unsigned short* vt     = (unsigned short*)(ws + (72u << 20));      // 16 MB
    float* biascat         = (float*)(ws + (88u << 20));               // 12 KB

    ln_kernel<<<M_TOTAL, 256, 0, stream>>>(x, gamma, beta, xn);
    dim3 tb(32, 8);
    transpose_cast<<<dim3(32, 32), tb, 0, stream>>>(Wq, wqkv_t, 1024, 1024);
    transpose_cast<<<dim3(32, 32), tb, 0, stream>>>(Wk, wqkv_t + 1024 * 1024, 1024, 1024);
    transpose_cast<<<dim3(32, 32), tb, 0, stream>>>(Wv, wqkv_t + 2 * 1024 * 1024, 1024, 1024);
    transpose_cast<<<dim3(32, 32), tb, 0, stream>>>(Wo, wo_t, 1024, 1024);
    bias_concat<<<12, 256, 0, stream>>>(bq, bk, bv, biascat);

    gemm128<0><<<dim3(N_QKV / 128, M_TOTAL / 128), 256, 0, stream>>>(
        xn, wqkv_t, biascat, nullptr, qkv, M_TOTAL, N_QKV, D_MODEL);

    transpose_v<<<dim3(SEQ / 64, BATCH * NHEADS), 256, 0, stream>>>(qkv, vt);

    attn_kernel<<<dim3(SEQ / 64, BATCH * NHEADS), 128, 0, stream>>>(qkv, vt, aout);

    gemm128<1><<<dim3(D_MODEL / 128, M_TOTAL / 128), 256, 0, stream>>>(
        aout, wo_t, bo, x, out, M_TOTAL, D_MODEL, D_MODEL);
}

// Round 5
// 385.031 us; speedup vs baseline: 1.5048x; 1.0138x over previous
//
#include <hip/hip_runtime.h>
#include <hip/hip_bf16.h>

#define D_MODEL 1024
#define NHEADS 16
#define DK 64
#define SEQ 2048
#define BATCH 4
#define M_TOTAL (BATCH * SEQ)   // 8192
#define N_QKV (3 * D_MODEL)     // 3072

// Q pre-scale folded into QKV-GEMM epilogue: 1/sqrt(64) * log2(e)
#define QSCALE 0.1803368801111f

typedef __attribute__((ext_vector_type(8))) short short8;
typedef __attribute__((ext_vector_type(4))) float f32x4;
typedef __attribute__((ext_vector_type(16))) float f32x16;

typedef const __attribute__((address_space(1))) unsigned int* gas_p;
typedef __attribute__((address_space(3))) unsigned int* las_p;

__device__ __forceinline__ void gl_lds16(const void* g, void* l) {
    __builtin_amdgcn_global_load_lds((gas_p)g, (las_p)l, 16, 0, 0);
}

__device__ __forceinline__ f32x4 mfma16(short8 a, short8 b, f32x4 c) {
    return __builtin_amdgcn_mfma_f32_16x16x32_bf16(a, b, c, 0, 0, 0);
}

__device__ __forceinline__ f32x16 mfma32(short8 a, short8 b, f32x16 c) {
    return __builtin_amdgcn_mfma_f32_32x32x16_bf16(a, b, c, 0, 0, 0);
}

__device__ __forceinline__ unsigned short f2bf(float f) {
    union { float f; unsigned int u; } v; v.f = f;
    unsigned int r = v.u + 0x7fffu + ((v.u >> 16) & 1u);
    return (unsigned short)(r >> 16);
}

// pack two f32 -> one u32 of 2 bf16 (RNE), hw instruction
__device__ __forceinline__ unsigned int cvtpk(float lo, float hi) {
    unsigned int r;
    asm("v_cvt_pk_bf16_f32 %0, %1, %2" : "=v"(r) : "v"(lo), "v"(hi));
    return r;
}
// swap: a' = {a.lo, b.lo}, b' = {a.hi, b.hi}  (lanes 32-63 of a <-> lanes 0-31 of b)
__device__ __forceinline__ void plswap(unsigned int& a, unsigned int& b) {
    asm("v_permlane32_swap_b32 %0, %1" : "+v"(a), "+v"(b));
}

// ---------------- LayerNorm: fp32 row -> bf16 normalized row ----------------
__global__ __launch_bounds__(256) void ln_kernel(const float* __restrict__ x,
                                                 const float* __restrict__ gamma,
                                                 const float* __restrict__ beta,
                                                 unsigned short* __restrict__ xn) {
    int row = blockIdx.x;
    int tid = threadIdx.x;
    const float4* xr = (const float4*)(x + (size_t)row * D_MODEL);
    float4 v = xr[tid];
    float s  = v.x + v.y + v.z + v.w;
    float ss = v.x * v.x + v.y * v.y + v.z * v.z + v.w * v.w;
    for (int off = 32; off > 0; off >>= 1) {
        s  += __shfl_down(s, off, 64);
        ss += __shfl_down(ss, off, 64);
    }
    __shared__ float red[8];
    int wid = tid >> 6;
    if ((tid & 63) == 0) { red[wid] = s; red[wid + 4] = ss; }
    __syncthreads();
    float st  = red[0] + red[1] + red[2] + red[3];
    float sst = red[4] + red[5] + red[6] + red[7];
    float mu  = st * (1.0f / D_MODEL);
    float var = sst * (1.0f / D_MODEL) - mu * mu;
    float rs  = rsqrtf(var + 1e-5f);
    const float4* g4 = (const float4*)gamma;
    const float4* b4 = (const float4*)beta;
    float4 g = g4[tid], b = b4[tid];
    ushort4 o;
    o.x = f2bf((v.x - mu) * rs * g.x + b.x);
    o.y = f2bf((v.y - mu) * rs * g.y + b.y);
    o.z = f2bf((v.z - mu) * rs * g.z + b.z);
    o.w = f2bf((v.w - mu) * rs * g.w + b.w);
    *(ushort4*)(xn + (size_t)row * D_MODEL + tid * 4) = o;
}

// -------- transpose + cast: src fp32 [K][N] -> dst bf16 [N][K] --------
__global__ __launch_bounds__(256) void transpose_cast(const float* __restrict__ src,
                                                      unsigned short* __restrict__ dst,
                                                      int K, int N) {
    __shared__ unsigned short tile[32][33];
    int n0 = blockIdx.x * 32;
    int k0 = blockIdx.y * 32;
    int tx = threadIdx.x;   // 0..31
    int ty = threadIdx.y;   // 0..7
    for (int i = 0; i < 4; i++) {
        int k = k0 + ty + i * 8;
        tile[ty + i * 8][tx] = f2bf(src[(size_t)k * N + n0 + tx]);
    }
    __syncthreads();
    for (int i = 0; i < 4; i++) {
        int n = n0 + ty + i * 8;
        dst[(size_t)n * K + k0 + tx] = tile[tx][ty + i * 8];
    }
}

__global__ void bias_concat(const float* __restrict__ bq, const float* __restrict__ bk,
                            const float* __restrict__ bv, float* __restrict__ cat) {
    int i = blockIdx.x * 256 + threadIdx.x;
    if (i < N_QKV)
        cat[i] = (i < 1024) ? bq[i] : (i < 2048 ? bk[i - 1024] : bv[i - 2048]);
}

// -------- V transpose: qkv [M][3072] V-part -> vt [bh][d][s] bf16 --------
__global__ __launch_bounds__(256) void transpose_v(const unsigned short* __restrict__ qkv,
                                                   unsigned short* __restrict__ vt) {
    __shared__ __align__(16) unsigned short tile[64 * 72];
    int s0 = blockIdx.x * 64;
    int bh = blockIdx.y;
    int b = bh >> 4, h = bh & 15;
    int tid = threadIdx.x;
    const unsigned short* src = qkv + (size_t)(b * SEQ + s0) * N_QKV + 2048 + h * DK;
    for (int it = 0; it < 2; it++) {
        int o = tid + it * 256;          // 0..511
        int sl = o >> 3, ck = o & 7;     // s-local row, chunk of 8 elems
        short8 v = *(const short8*)(src + (size_t)sl * N_QKV + ck * 8);
        *(short8*)&tile[sl * 72 + ((ck ^ ((sl >> 3) & 7)) * 8)] = v;
    }
    __syncthreads();
    unsigned short* dst = vt + (size_t)bh * DK * SEQ + s0;
    for (int it = 0; it < 2; it++) {
        int o = tid + it * 256;
        int d = o >> 3, sc = (o & 7) * 8;
        short8 v;
        for (int i = 0; i < 8; i++)
            ((unsigned short*)&v)[i] =
                tile[(sc + i) * 72 + (((d >> 3) ^ (o & 7)) * 8) + (d & 7)];
        *(short8*)(dst + (size_t)d * SEQ + sc) = v;
    }
}

// -------- GEMM (m97 structure): C[M][N] = A[M][K](bf16) x Bt[N][K](bf16)^T --------
// MODE 0: bf16 output + bias; Q columns (c < D_MODEL) pre-scaled by QSCALE so
//         attention scores land in exp2 domain with 1/sqrt(dk) applied.
// MODE 1: fp32 output + bias + residual.
template <int MODE>
__global__ __launch_bounds__(256) void gemm128(const unsigned short* __restrict__ A,
                                               const unsigned short* __restrict__ Bt,
                                               const float* __restrict__ bias,
                                               const float* __restrict__ residual,
                                               void* __restrict__ Cout,
                                               int M, int N, int K) {
    constexpr int BM = 128, BN = 128, BK = 32;
    __shared__ __align__(16) unsigned short As[BM * BK];
    __shared__ __align__(16) unsigned short Bs[BN * BK];
    int m0 = blockIdx.y * BM;
    int n0 = blockIdx.x * BN;
    int tid = threadIdx.x;
    int wave = tid >> 6, lane = tid & 63;
    int wm = wave >> 1, wn = wave & 1;
    f32x4 acc[4][4] = {};

    int srow = wave * 32 + (lane >> 2);
    int scol = (lane & 3) * 8;
    const unsigned short* Ag0 = A + (size_t)(m0 + srow) * K + scol;
    const unsigned short* Ag1 = A + (size_t)(m0 + srow + 16) * K + scol;
    const unsigned short* Bg0 = Bt + (size_t)(n0 + srow) * K + scol;
    const unsigned short* Bg1 = Bt + (size_t)(n0 + srow + 16) * K + scol;
    unsigned short* Al0 = &As[(wave * 32) * BK];
    unsigned short* Al1 = &As[(wave * 32 + 16) * BK];
    unsigned short* Bl0 = &Bs[(wave * 32) * BK];
    unsigned short* Bl1 = &Bs[(wave * 32 + 16) * BK];

    int fr = lane & 15;
    int fq = lane >> 4;
    for (int k0 = 0; k0 < K; k0 += BK) {
        gl_lds16(Ag0 + k0, Al0);
        gl_lds16(Ag1 + k0, Al1);
        gl_lds16(Bg0 + k0, Bl0);
        gl_lds16(Bg1 + k0, Bl1);
        __syncthreads();
        short8 a[4], b[4];
        for (int ms = 0; ms < 4; ms++)
            a[ms] = *(short8*)&As[(wm * 64 + ms * 16 + fr) * BK + fq * 8];
        for (int ns = 0; ns < 4; ns++)
            b[ns] = *(short8*)&Bs[(wn * 64 + ns * 16 + fr) * BK + fq * 8];
        for (int ms = 0; ms < 4; ms++)
            for (int ns = 0; ns < 4; ns++)
                acc[ms][ns] = mfma16(a[ms], b[ns], acc[ms][ns]);
        __syncthreads();
    }
    for (int ms = 0; ms < 4; ms++)
        for (int ns = 0; ns < 4; ns++)
            for (int i = 0; i < 4; i++) {
                int r = m0 + wm * 64 + ms * 16 + fq * 4 + i;
                int c = n0 + wn * 64 + ns * 16 + fr;
                float val = acc[ms][ns][i] + bias[c];
                if (MODE == 0) {
                    if (c < D_MODEL) val *= QSCALE;   // Q pre-scale (exp2 domain)
                    ((unsigned short*)Cout)[(size_t)r * N + c] = f2bf(val);
                } else {
                    ((float*)Cout)[(size_t)r * N + c] = val + residual[(size_t)r * N + c];
                }
            }
}

// -------- causal flash attention, swapped-QK^T 32x32 structure --------
// qb reversed (LPT): longest strips dispatch first, short ones backfill tail.
// Scores arrive in exp2 domain (Q pre-scaled in QKV GEMM) -> bare v_exp_f32.
// Tree max/sum reductions; defer-max rescale (T13); setprio around MFMA (T5).
__global__ __launch_bounds__(128, 4) void attn_kernel(const unsigned short* __restrict__ qkv,
                                                      const unsigned short* __restrict__ vt,
                                                      unsigned short* __restrict__ attn_out) {
    __shared__ __align__(16) unsigned short Ks[2][64 * 64];
    __shared__ __align__(16) unsigned short Vs[2][64 * 64];
    int qb = gridDim.x - 1 - blockIdx.x;   // LPT: long strips first
    int bh = blockIdx.y;
    int b = bh >> 4, h = bh & 15;
    int tid = threadIdx.x, w = tid >> 6, lane = tid & 63;
    int l5 = lane >> 5;             // hi half
    int q31 = lane & 31;
    int l7 = lane & 7;
    int qg = qb * 64 + w * 32 + q31;   // this lane's global q row

    const unsigned short* kbase = qkv + (size_t)(b * SEQ) * N_QKV + D_MODEL + h * DK;
    const unsigned short* vtb = vt + (size_t)bh * DK * SEQ;

    // Q B-fragments: lane q-row, k-slot s covers d = 16s + 8*l5 + {0..7}
    const unsigned short* qptr = qkv + (size_t)(b * SEQ + qg) * N_QKV + h * DK;
    short8 qf[4];
#pragma unroll
    for (int s = 0; s < 4; s++)
        qf[s] = *(const short8*)(qptr + 16 * s + 8 * l5);

    int srow = lane >> 3;                  // 0..7 within 8-row group
    int schunk = (l7 ^ srow) * 8;          // pre-swizzled global chunk (m173)

    f32x16 ot0 = {}, ot1 = {};
    float mold = -1e30f, lsum = 0.f;

#pragma unroll
    for (int c = 0; c < 4; c++) {
        int rl_ = w * 32 + c * 8;
        gl_lds16(kbase + (size_t)(rl_ + srow) * N_QKV + schunk, &Ks[0][rl_ * 64]);
        gl_lds16(vtb + (size_t)(rl_ + srow) * SEQ + schunk, &Vs[0][rl_ * 64]);
    }
    __syncthreads();

    for (int j = 0; j <= qb; j++) {
        int bb = j & 1;
        if (j < qb) {
#pragma unroll
            for (int c = 0; c < 4; c++) {
                int rl_ = w * 32 + c * 8;
                gl_lds16(kbase + (size_t)((j + 1) * 64 + rl_ + srow) * N_QKV + schunk,
                         &Ks[bb ^ 1][rl_ * 64]);
                gl_lds16(vtb + (size_t)(rl_ + srow) * SEQ + (j + 1) * 64 + schunk,
                         &Vs[bb ^ 1][rl_ * 64]);
            }
        }
        const unsigned short* kb = Ks[bb];
        const unsigned short* vb = Vs[bb];
        // S^T = K . Q^T : two 32-kv tiles, chain over 4 k-slots
        f32x16 s0 = {}, s1 = {};
        __builtin_amdgcn_s_setprio(1);
#pragma unroll
        for (int s = 0; s < 4; s++) {
            int co = (((s << 1) | l5) ^ l7) * 8;
            short8 k0 = *(const short8*)&kb[(q31) * 64 + co];
            short8 k1 = *(const short8*)&kb[(32 + q31) * 64 + co];
            s0 = mfma32(k0, qf[s], s0);
            s1 = mfma32(k1, qf[s], s1);
        }
        __builtin_amdgcn_s_setprio(0);
        // causal mask on diagonal tile only (scores already scaled, exp2 domain)
        if (j == qb) {
#pragma unroll
            for (int r = 0; r < 16; r++) {
                int kv0 = j * 64 + (r & 3) + 8 * (r >> 2) + 4 * l5;
                if (kv0 > qg) s0[r] = -1e30f;
                if (kv0 + 32 > qg) s1[r] = -1e30f;
            }
        }
        // tree max over 32 regs (depth 6), then cross-half shfl
        float tm[16];
#pragma unroll
        for (int r = 0; r < 16; r++) tm[r] = fmaxf(s0[r], s1[r]);
#pragma unroll
        for (int st = 8; st > 0; st >>= 1)
#pragma unroll
            for (int r = 0; r < 8; r++)
                if (r < st) tm[r] = fmaxf(tm[r], tm[r + st]);
        float mloc = fmaxf(tm[0], __shfl_xor(tm[0], 32));
        // defer-max (T13): rescale only when max grew beyond 2^11 headroom
        if (!__all(mloc - mold <= 11.0f)) {
            float mnew = fmaxf(mold, mloc);
            float aexp = exp2f(mold - mnew);
            lsum *= aexp;
#pragma unroll
            for (int r = 0; r < 16; r++) { ot0[r] *= aexp; ot1[r] *= aexp; }
            mold = mnew;
        }
        // P = exp2(s - mold)  (bare v_exp_f32), tree sum
        float ts[16];
#pragma unroll
        for (int r = 0; r < 16; r++) {
            s0[r] = exp2f(s0[r] - mold);
            s1[r] = exp2f(s1[r] - mold);
            ts[r] = s0[r] + s1[r];
        }
#pragma unroll
        for (int st = 8; st > 0; st >>= 1)
#pragma unroll
            for (int r = 0; r < 8; r++)
                if (r < st) ts[r] += ts[r + st];
        lsum += ts[0] + __shfl_xor(ts[0], 32);

        // P -> bf16 B-fragments via cvt_pk + permlane32_swap; PV accumulate
        union { unsigned int wd[4]; short8 v; } pf;
#pragma unroll
        for (int t = 0; t < 4; t++) {
            int b2 = t & 1;
            unsigned int pa, pb, pc, pd;
            if (t < 2) {
                pa = cvtpk(s0[8 * b2 + 0], s0[8 * b2 + 1]);
                pb = cvtpk(s0[8 * b2 + 2], s0[8 * b2 + 3]);
                pc = cvtpk(s0[8 * b2 + 4], s0[8 * b2 + 5]);
                pd = cvtpk(s0[8 * b2 + 6], s0[8 * b2 + 7]);
            } else {
                pa = cvtpk(s1[8 * b2 + 0], s1[8 * b2 + 1]);
                pb = cvtpk(s1[8 * b2 + 2], s1[8 * b2 + 3]);
                pc = cvtpk(s1[8 * b2 + 4], s1[8 * b2 + 5]);
                pd = cvtpk(s1[8 * b2 + 6], s1[8 * b2 + 7]);
            }
            plswap(pa, pc);
            plswap(pb, pd);
            pf.wd[0] = pa; pf.wd[1] = pb; pf.wd[2] = pc; pf.wd[3] = pd;
            int co = (((t << 1) | l5) ^ l7) * 8;
            short8 v0 = *(const short8*)&vb[(q31) * 64 + co];
            short8 v1 = *(const short8*)&vb[(32 + q31) * 64 + co];
            __builtin_amdgcn_s_setprio(1);
            ot0 = mfma32(v0, pf.v, ot0);
            ot1 = mfma32(v1, pf.v, ot1);
            __builtin_amdgcn_s_setprio(0);
        }
        __syncthreads();   // drains this wave's staging loads, releases buffers
    }

    // epilogue: O^T[d][q] -> attn_out[q][h*64+d], divide by lsum, pack bf16
    float rl = 1.0f / lsum;
    unsigned short* ob = attn_out + (size_t)(b * SEQ + qg) * D_MODEL + h * DK + 4 * l5;
#pragma unroll
    for (int qq = 0; qq < 4; qq++) {
        uint2 val;
        val.x = cvtpk(ot0[4 * qq + 0] * rl, ot0[4 * qq + 1] * rl);
        val.y = cvtpk(ot0[4 * qq + 2] * rl, ot0[4 * qq + 3] * rl);
        *(uint2*)(ob + 8 * qq) = val;
        val.x = cvtpk(ot1[4 * qq + 0] * rl, ot1[4 * qq + 1] * rl);
        val.y = cvtpk(ot1[4 * qq + 2] * rl, ot1[4 * qq + 3] * rl);
        *(uint2*)(ob + 32 + 8 * qq) = val;
    }
}

extern "C" void kernel_launch(void* const* d_in, const int* in_sizes, int n_in,
                              void* d_out, int out_size, void* d_ws, size_t ws_size,
                              hipStream_t stream) {
    const float* x     = (const float*)d_in[0];
    const float* Wq    = (const float*)d_in[1];
    const float* bq    = (const float*)d_in[2];
    const float* Wk    = (const float*)d_in[3];
    const float* bk    = (const float*)d_in[4];
    const float* Wv    = (const float*)d_in[5];
    const float* bv    = (const float*)d_in[6];
    const float* Wo    = (const float*)d_in[7];
    const float* bo    = (const float*)d_in[8];
    const float* gamma = (const float*)d_in[9];
    const float* beta  = (const float*)d_in[10];
    float* out = (float*)d_out;

    char* ws = (char*)d_ws;
    unsigned short* xn     = (unsigned short*)ws;                      // 16 MB (dead after QKV gemm)
    unsigned short* aout   = xn;                                       // alias
    unsigned short* wqkv_t = (unsigned short*)(ws + (16u << 20));      // 6 MB
    unsigned short* wo_t   = (unsigned short*)(ws + (22u << 20));      // 2 MB
    unsigned short* qkv    = (unsigned short*)(ws + (24u << 20));      // 48 MB
    unsigned short* vt     = (unsigned short*)(ws + (72u << 20));      // 16 MB
    float* biascat         = (float*)(ws + (88u << 20));               // 12 KB

    ln_kernel<<<M_TOTAL, 256, 0, stream>>>(x, gamma, beta, xn);
    dim3 tb(32, 8);
    transpose_cast<<<dim3(32, 32), tb, 0, stream>>>(Wq, wqkv_t, 1024, 1024);
    transpose_cast<<<dim3(32, 32), tb, 0, stream>>>(Wk, wqkv_t + 1024 * 1024, 1024, 1024);
    transpose_cast<<<dim3(32, 32), tb, 0, stream>>>(Wv, wqkv_t + 2 * 1024 * 1024, 1024, 1024);
    transpose_cast<<<dim3(32, 32), tb, 0, stream>>>(Wo, wo_t, 1024, 1024);
    bias_concat<<<12, 256, 0, stream>>>(bq, bk, bv, biascat);

    gemm128<0><<<dim3(N_QKV / 128, M_TOTAL / 128), 256, 0, stream>>>(
        xn, wqkv_t, biascat, nullptr, qkv, M_TOTAL, N_QKV, D_MODEL);

    transpose_v<<<dim3(SEQ / 64, BATCH * NHEADS), 256, 0, stream>>>(qkv, vt);

    attn_kernel<<<dim3(SEQ / 64, BATCH * NHEADS), 128, 0, stream>>>(qkv, vt, aout);

    gemm128<1><<<dim3(D_MODEL / 128, M_TOTAL / 128), 256, 0, stream>>>(
        aout, wo_t, bo, x, out, M_TOTAL, D_MODEL, D_MODEL);
}

// Round 8
// 303.003 us; speedup vs baseline: 1.9122x; 1.2707x over previous
//
#include <hip/hip_runtime.h>
#include <hip/hip_bf16.h>

#define D_MODEL 1024
#define NHEADS 16
#define DK 64
#define SEQ 2048
#define BATCH 4
#define M_TOTAL (BATCH * SEQ)   // 8192
#define N_QKV (3 * D_MODEL)     // 3072

// Q pre-scale folded into QKV-GEMM epilogue: 1/sqrt(64) * log2(e)
#define QSCALE 0.1803368801111f

typedef __attribute__((ext_vector_type(8))) short short8;
typedef __attribute__((ext_vector_type(4))) float f32x4;
typedef __attribute__((ext_vector_type(16))) float f32x16;

typedef const __attribute__((address_space(1))) unsigned int* gas_p;
typedef __attribute__((address_space(3))) unsigned int* las_p;

__device__ __forceinline__ void gl_lds16(const void* g, void* l) {
    __builtin_amdgcn_global_load_lds((gas_p)g, (las_p)l, 16, 0, 0);
}

__device__ __forceinline__ f32x4 mfma16(short8 a, short8 b, f32x4 c) {
    return __builtin_amdgcn_mfma_f32_16x16x32_bf16(a, b, c, 0, 0, 0);
}

__device__ __forceinline__ f32x16 mfma32(short8 a, short8 b, f32x16 c) {
    return __builtin_amdgcn_mfma_f32_32x32x16_bf16(a, b, c, 0, 0, 0);
}

__device__ __forceinline__ unsigned short f2bf(float f) {
    union { float f; unsigned int u; } v; v.f = f;
    unsigned int r = v.u + 0x7fffu + ((v.u >> 16) & 1u);
    return (unsigned short)(r >> 16);
}

__device__ __forceinline__ unsigned int cvtpk(float lo, float hi) {
    unsigned int r;
    asm("v_cvt_pk_bf16_f32 %0, %1, %2" : "=v"(r) : "v"(lo), "v"(hi));
    return r;
}
__device__ __forceinline__ void plswap(unsigned int& a, unsigned int& b) {
    asm("v_permlane32_swap_b32 %0, %1" : "+v"(a), "+v"(b));
}

// ---------------- LayerNorm: fp32 row -> bf16 normalized row ----------------
__global__ __launch_bounds__(256) void ln_kernel(const float* __restrict__ x,
                                                 const float* __restrict__ gamma,
                                                 const float* __restrict__ beta,
                                                 unsigned short* __restrict__ xn) {
    int row = blockIdx.x;
    int tid = threadIdx.x;
    const float4* xr = (const float4*)(x + (size_t)row * D_MODEL);
    float4 v = xr[tid];
    float s  = v.x + v.y + v.z + v.w;
    float ss = v.x * v.x + v.y * v.y + v.z * v.z + v.w * v.w;
    for (int off = 32; off > 0; off >>= 1) {
        s  += __shfl_down(s, off, 64);
        ss += __shfl_down(ss, off, 64);
    }
    __shared__ float red[8];
    int wid = tid >> 6;
    if ((tid & 63) == 0) { red[wid] = s; red[wid + 4] = ss; }
    __syncthreads();
    float st  = red[0] + red[1] + red[2] + red[3];
    float sst = red[4] + red[5] + red[6] + red[7];
    float mu  = st * (1.0f / D_MODEL);
    float var = sst * (1.0f / D_MODEL) - mu * mu;
    float rs  = rsqrtf(var + 1e-5f);
    const float4* g4 = (const float4*)gamma;
    const float4* b4 = (const float4*)beta;
    float4 g = g4[tid], b = b4[tid];
    ushort4 o;
    o.x = f2bf((v.x - mu) * rs * g.x + b.x);
    o.y = f2bf((v.y - mu) * rs * g.y + b.y);
    o.z = f2bf((v.z - mu) * rs * g.z + b.z);
    o.w = f2bf((v.w - mu) * rs * g.w + b.w);
    *(ushort4*)(xn + (size_t)row * D_MODEL + tid * 4) = o;
}

// -------- transpose + cast: src fp32 [K][N] -> dst bf16 [N][K] --------
__global__ __launch_bounds__(256) void transpose_cast(const float* __restrict__ src,
                                                      unsigned short* __restrict__ dst,
                                                      int K, int N) {
    __shared__ unsigned short tile[32][33];
    int n0 = blockIdx.x * 32;
    int k0 = blockIdx.y * 32;
    int tx = threadIdx.x;   // 0..31
    int ty = threadIdx.y;   // 0..7
    for (int i = 0; i < 4; i++) {
        int k = k0 + ty + i * 8;
        tile[ty + i * 8][tx] = f2bf(src[(size_t)k * N + n0 + tx]);
    }
    __syncthreads();
    for (int i = 0; i < 4; i++) {
        int n = n0 + ty + i * 8;
        dst[(size_t)n * K + k0 + tx] = tile[tx][ty + i * 8];
    }
}

__global__ void bias_concat(const float* __restrict__ bq, const float* __restrict__ bk,
                            const float* __restrict__ bv, float* __restrict__ cat) {
    int i = blockIdx.x * 256 + threadIdx.x;
    if (i < N_QKV)
        cat[i] = (i < 1024) ? bq[i] : (i < 2048 ? bk[i - 1024] : bv[i - 2048]);
}

// -------- V transpose: qkv [M][3072] V-part -> vt [bh][d][s] bf16 --------
__global__ __launch_bounds__(256) void transpose_v(const unsigned short* __restrict__ qkv,
                                                   unsigned short* __restrict__ vt) {
    __shared__ __align__(16) unsigned short tile[64 * 72];
    int s0 = blockIdx.x * 64;
    int bh = blockIdx.y;
    int b = bh >> 4, h = bh & 15;
    int tid = threadIdx.x;
    const unsigned short* src = qkv + (size_t)(b * SEQ + s0) * N_QKV + 2048 + h * DK;
    for (int it = 0; it < 2; it++) {
        int o = tid + it * 256;          // 0..511
        int sl = o >> 3, ck = o & 7;     // s-local row, chunk of 8 elems
        short8 v = *(const short8*)(src + (size_t)sl * N_QKV + ck * 8);
        *(short8*)&tile[sl * 72 + ((ck ^ ((sl >> 3) & 7)) * 8)] = v;
    }
    __syncthreads();
    unsigned short* dst = vt + (size_t)bh * DK * SEQ + s0;
    for (int it = 0; it < 2; it++) {
        int o = tid + it * 256;
        int d = o >> 3, sc = (o & 7) * 8;
        short8 v;
        for (int i = 0; i < 8; i++)
            ((unsigned short*)&v)[i] =
                tile[(sc + i) * 72 + (((d >> 3) ^ (o & 7)) * 8) + (d & 7)];
        *(short8*)(dst + (size_t)d * SEQ + sc) = v;
    }
}

// -------- GEMM (m97 structure): C[M][N] = A[M][K](bf16) x Bt[N][K](bf16)^T --------
template <int MODE>
__global__ __launch_bounds__(256) void gemm128(const unsigned short* __restrict__ A,
                                               const unsigned short* __restrict__ Bt,
                                               const float* __restrict__ bias,
                                               const float* __restrict__ residual,
                                               void* __restrict__ Cout,
                                               int M, int N, int K) {
    constexpr int BM = 128, BN = 128, BK = 32;
    __shared__ __align__(16) unsigned short As[BM * BK];
    __shared__ __align__(16) unsigned short Bs[BN * BK];
    int m0 = blockIdx.y * BM;
    int n0 = blockIdx.x * BN;
    int tid = threadIdx.x;
    int wave = tid >> 6, lane = tid & 63;
    int wm = wave >> 1, wn = wave & 1;
    f32x4 acc[4][4] = {};

    int srow = wave * 32 + (lane >> 2);
    int scol = (lane & 3) * 8;
    const unsigned short* Ag0 = A + (size_t)(m0 + srow) * K + scol;
    const unsigned short* Ag1 = A + (size_t)(m0 + srow + 16) * K + scol;
    const unsigned short* Bg0 = Bt + (size_t)(n0 + srow) * K + scol;
    const unsigned short* Bg1 = Bt + (size_t)(n0 + srow + 16) * K + scol;
    unsigned short* Al0 = &As[(wave * 32) * BK];
    unsigned short* Al1 = &As[(wave * 32 + 16) * BK];
    unsigned short* Bl0 = &Bs[(wave * 32) * BK];
    unsigned short* Bl1 = &Bs[(wave * 32 + 16) * BK];

    int fr = lane & 15;
    int fq = lane >> 4;
    for (int k0 = 0; k0 < K; k0 += BK) {
        gl_lds16(Ag0 + k0, Al0);
        gl_lds16(Ag1 + k0, Al1);
        gl_lds16(Bg0 + k0, Bl0);
        gl_lds16(Bg1 + k0, Bl1);
        __syncthreads();
        short8 a[4], b[4];
        for (int ms = 0; ms < 4; ms++)
            a[ms] = *(short8*)&As[(wm * 64 + ms * 16 + fr) * BK + fq * 8];
        for (int ns = 0; ns < 4; ns++)
            b[ns] = *(short8*)&Bs[(wn * 64 + ns * 16 + fr) * BK + fq * 8];
        for (int ms = 0; ms < 4; ms++)
            for (int ns = 0; ns < 4; ns++)
                acc[ms][ns] = mfma16(a[ms], b[ns], acc[ms][ns]);
        __syncthreads();
    }
    for (int ms = 0; ms < 4; ms++)
        for (int ns = 0; ns < 4; ns++)
            for (int i = 0; i < 4; i++) {
                int r = m0 + wm * 64 + ms * 16 + fq * 4 + i;
                int c = n0 + wn * 64 + ns * 16 + fr;
                float val = acc[ms][ns][i] + bias[c];
                if (MODE == 0) {
                    if (c < D_MODEL) val *= QSCALE;   // Q pre-scale (exp2 domain)
                    ((unsigned short*)Cout)[(size_t)r * N + c] = f2bf(val);
                } else {
                    ((float*)Cout)[(size_t)r * N + c] = val + residual[(size_t)r * N + c];
                }
            }
}

// -------- causal flash attention, swapped-QK^T 32x32, 4-wave/128-row strips --------
// 1D grid, globally LPT-sorted: n -> qs = NSTRIP-1 - n/64 (longest strips first),
// bh = n%64 (same-bh blocks land on the same XCD: stride 64 = 0 mod 8).
// 1024 blocks x 32KB LDS -> all blocks co-resident (5/CU), 20 waves/CU.
// Wave w owns q rows strip+w*32..+31; skips tiles entirely above its diagonal.
__global__ __launch_bounds__(256, 4) void attn_kernel(const unsigned short* __restrict__ qkv,
                                                      const unsigned short* __restrict__ vt,
                                                      unsigned short* __restrict__ attn_out) {
    __shared__ __align__(16) unsigned short Ks[2][64 * 64];
    __shared__ __align__(16) unsigned short Vs[2][64 * 64];
    constexpr int NSTRIP = SEQ / 128;                 // 16
    int n = blockIdx.x;
    int qs = NSTRIP - 1 - (n >> 6);                   // LPT: long strips first
    int bh = n & 63;
    int b = bh >> 4, h = bh & 15;
    int tid = threadIdx.x, w = tid >> 6, lane = tid & 63;
    int l5 = lane >> 5;
    int q31 = lane & 31;
    int l7 = lane & 7;
    int S0 = qs * 128;
    int qg = S0 + w * 32 + q31;                       // this lane's global q row
    int jmax = 2 * qs + 1;                            // kv tiles 0..jmax
    int jd = 2 * qs + (w >> 1);                       // wave's diagonal tile

    const unsigned short* kbase = qkv + (size_t)(b * SEQ) * N_QKV + D_MODEL + h * DK;
    const unsigned short* vtb = vt + (size_t)bh * DK * SEQ;

    // Q B-fragments: lane q-row, k-slot s covers d = 16s + 8*l5 + {0..7}
    const unsigned short* qptr = qkv + (size_t)(b * SEQ + qg) * N_QKV + h * DK;
    short8 qf[4];
#pragma unroll
    for (int s = 0; s < 4; s++)
        qf[s] = *(const short8*)(qptr + 16 * s + 8 * l5);

    int srow = lane >> 3;                  // 0..7 within 8-row group
    int schunk = (l7 ^ srow) * 8;          // pre-swizzled global chunk (m173)

    f32x16 ot0 = {}, ot1 = {};
    float mold = -1e30f, lsum = 0.f;

    // prologue: stage tile 0; wave w stages rows w*16..w*16+15 of K and V
#pragma unroll
    for (int c = 0; c < 2; c++) {
        int rl_ = w * 16 + c * 8;
        gl_lds16(kbase + (size_t)(rl_ + srow) * N_QKV + schunk, &Ks[0][rl_ * 64]);
        gl_lds16(vtb + (size_t)(rl_ + srow) * SEQ + schunk, &Vs[0][rl_ * 64]);
    }
    __syncthreads();

    for (int j = 0; j <= jmax; j++) {
        int bb = j & 1;
        if (j < jmax) {
#pragma unroll
            for (int c = 0; c < 2; c++) {
                int rl_ = w * 16 + c * 8;
                gl_lds16(kbase + (size_t)((j + 1) * 64 + rl_ + srow) * N_QKV + schunk,
                         &Ks[bb ^ 1][rl_ * 64]);
                gl_lds16(vtb + (size_t)(rl_ + srow) * SEQ + (j + 1) * 64 + schunk,
                         &Vs[bb ^ 1][rl_ * 64]);
            }
        }
        if (j <= jd) {   // tiles beyond the wave's diagonal are fully masked: skip
            const unsigned short* kb = Ks[bb];
            const unsigned short* vb = Vs[bb];
            f32x16 s0 = {}, s1 = {};
            __builtin_amdgcn_s_setprio(1);
#pragma unroll
            for (int s = 0; s < 4; s++) {
                int co = (((s << 1) | l5) ^ l7) * 8;
                short8 k0 = *(const short8*)&kb[(q31) * 64 + co];
                short8 k1 = *(const short8*)&kb[(32 + q31) * 64 + co];
                s0 = mfma32(k0, qf[s], s0);
                s1 = mfma32(k1, qf[s], s1);
            }
            __builtin_amdgcn_s_setprio(0);
            if (j == jd) {
#pragma unroll
                for (int r = 0; r < 16; r++) {
                    int kv0 = j * 64 + (r & 3) + 8 * (r >> 2) + 4 * l5;
                    if (kv0 > qg) s0[r] = -1e30f;
                    if (kv0 + 32 > qg) s1[r] = -1e30f;
                }
            }
            // tree max (depth 6) + cross-half shfl
            float tm[16];
#pragma unroll
            for (int r = 0; r < 16; r++) tm[r] = fmaxf(s0[r], s1[r]);
#pragma unroll
            for (int st = 8; st > 0; st >>= 1)
#pragma unroll
                for (int r = 0; r < 8; r++)
                    if (r < st) tm[r] = fmaxf(tm[r], tm[r + st]);
            float mloc = fmaxf(tm[0], __shfl_xor(tm[0], 32));
            // defer-max (T13): rescale only when max grew past 2^11 headroom
            if (!__all(mloc - mold <= 11.0f)) {
                float mnew = fmaxf(mold, mloc);
                float aexp = exp2f(mold - mnew);
                lsum *= aexp;
#pragma unroll
                for (int r = 0; r < 16; r++) { ot0[r] *= aexp; ot1[r] *= aexp; }
                mold = mnew;
            }
            // P = exp2(s - mold), tree sum
            float ts[16];
#pragma unroll
            for (int r = 0; r < 16; r++) {
                s0[r] = exp2f(s0[r] - mold);
                s1[r] = exp2f(s1[r] - mold);
                ts[r] = s0[r] + s1[r];
            }
#pragma unroll
            for (int st = 8; st > 0; st >>= 1)
#pragma unroll
                for (int r = 0; r < 8; r++)
                    if (r < st) ts[r] += ts[r + st];
            lsum += ts[0] + __shfl_xor(ts[0], 32);

            // P -> bf16 B-fragments via cvt_pk + permlane32_swap; PV accumulate
            union { unsigned int wd[4]; short8 v; } pf;
#pragma unroll
            for (int t = 0; t < 4; t++) {
                int b2 = t & 1;
                unsigned int pa, pb, pc, pd;
                if (t < 2) {
                    pa = cvtpk(s0[8 * b2 + 0], s0[8 * b2 + 1]);
                    pb = cvtpk(s0[8 * b2 + 2], s0[8 * b2 + 3]);
                    pc = cvtpk(s0[8 * b2 + 4], s0[8 * b2 + 5]);
                    pd = cvtpk(s0[8 * b2 + 6], s0[8 * b2 + 7]);
                } else {
                    pa = cvtpk(s1[8 * b2 + 0], s1[8 * b2 + 1]);
                    pb = cvtpk(s1[8 * b2 + 2], s1[8 * b2 + 3]);
                    pc = cvtpk(s1[8 * b2 + 4], s1[8 * b2 + 5]);
                    pd = cvtpk(s1[8 * b2 + 6], s1[8 * b2 + 7]);
                }
                plswap(pa, pc);
                plswap(pb, pd);
                pf.wd[0] = pa; pf.wd[1] = pb; pf.wd[2] = pc; pf.wd[3] = pd;
                int co = (((t << 1) | l5) ^ l7) * 8;
                short8 v0 = *(const short8*)&vb[(q31) * 64 + co];
                short8 v1 = *(const short8*)&vb[(32 + q31) * 64 + co];
                __builtin_amdgcn_s_setprio(1);
                ot0 = mfma32(v0, pf.v, ot0);
                ot1 = mfma32(v1, pf.v, ot1);
                __builtin_amdgcn_s_setprio(0);
            }
        }
        __syncthreads();   // drains staging loads, releases buffers
    }

    // epilogue: O^T[d][q] -> attn_out[q][h*64+d], divide by lsum, pack bf16
    float rl = 1.0f / lsum;
    unsigned short* ob = attn_out + (size_t)(b * SEQ + qg) * D_MODEL + h * DK + 4 * l5;
#pragma unroll
    for (int qq = 0; qq < 4; qq++) {
        uint2 val;
        val.x = cvtpk(ot0[4 * qq + 0] * rl, ot0[4 * qq + 1] * rl);
        val.y = cvtpk(ot0[4 * qq + 2] * rl, ot0[4 * qq + 3] * rl);
        *(uint2*)(ob + 8 * qq) = val;
        val.x = cvtpk(ot1[4 * qq + 0] * rl, ot1[4 * qq + 1] * rl);
        val.y = cvtpk(ot1[4 * qq + 2] * rl, ot1[4 * qq + 3] * rl);
        *(uint2*)(ob + 32 + 8 * qq) = val;
    }
}

extern "C" void kernel_launch(void* const* d_in, const int* in_sizes, int n_in,
                              void* d_out, int out_size, void* d_ws, size_t ws_size,
                              hipStream_t stream) {
    const float* x     = (const float*)d_in[0];
    const float* Wq    = (const float*)d_in[1];
    const float* bq    = (const float*)d_in[2];
    const float* Wk    = (const float*)d_in[3];
    const float* bk    = (const float*)d_in[4];
    const float* Wv    = (const float*)d_in[5];
    const float* bv    = (const float*)d_in[6];
    const float* Wo    = (const float*)d_in[7];
    const float* bo    = (const float*)d_in[8];
    const float* gamma = (const float*)d_in[9];
    const float* beta  = (const float*)d_in[10];
    float* out = (float*)d_out;

    char* ws = (char*)d_ws;
    unsigned short* xn     = (unsigned short*)ws;                      // 16 MB (dead after QKV gemm)
    unsigned short* aout   = xn;                                       // alias
    unsigned short* wqkv_t = (unsigned short*)(ws + (16u << 20));      // 6 MB
    unsigned short* wo_t   = (unsigned short*)(ws + (22u << 20));      // 2 MB
    unsigned short* qkv    = (unsigned short*)(ws + (24u << 20));      // 48 MB
    unsigned short* vt     = (unsigned short*)(ws + (72u << 20));      // 16 MB
    float* biascat         = (float*)(ws + (88u << 20));               // 12 KB

    ln_kernel<<<M_TOTAL, 256, 0, stream>>>(x, gamma, beta, xn);
    dim3 tb(32, 8);
    transpose_cast<<<dim3(32, 32), tb, 0, stream>>>(Wq, wqkv_t, 1024, 1024);
    transpose_cast<<<dim3(32, 32), tb, 0, stream>>>(Wk, wqkv_t + 1024 * 1024, 1024, 1024);
    transpose_cast<<<dim3(32, 32), tb, 0, stream>>>(Wv, wqkv_t + 2 * 1024 * 1024, 1024, 1024);
    transpose_cast<<<dim3(32, 32), tb, 0, stream>>>(Wo, wo_t, 1024, 1024);
    bias_concat<<<12, 256, 0, stream>>>(bq, bk, bv, biascat);

    gemm128<0><<<dim3(N_QKV / 128, M_TOTAL / 128), 256, 0, stream>>>(
        xn, wqkv_t, biascat, nullptr, qkv, M_TOTAL, N_QKV, D_MODEL);

    transpose_v<<<dim3(SEQ / 64, BATCH * NHEADS), 256, 0, stream>>>(qkv, vt);

    attn_kernel<<<dim3((SEQ / 128) * BATCH * NHEADS), 256, 0, stream>>>(qkv, vt, aout);

    gemm128<1><<<dim3(D_MODEL / 128, M_TOTAL / 128), 256, 0, stream>>>(
        aout, wo_t, bo, x, out, M_TOTAL, D_MODEL, D_MODEL);
}

// Round 9
// 283.708 us; speedup vs baseline: 2.0422x; 1.0680x over previous
//
#include <hip/hip_runtime.h>
#include <hip/hip_bf16.h>

#define D_MODEL 1024
#define NHEADS 16
#define DK 64
#define SEQ 2048
#define BATCH 4
#define M_TOTAL (BATCH * SEQ)   // 8192
#define N_QKV (3 * D_MODEL)     // 3072

// Q pre-scale folded into QKV-GEMM epilogue: 1/sqrt(64) * log2(e)
#define QSCALE 0.1803368801111f

typedef __attribute__((ext_vector_type(8))) short short8;
typedef __attribute__((ext_vector_type(4))) float f32x4;
typedef __attribute__((ext_vector_type(16))) float f32x16;

typedef const __attribute__((address_space(1))) unsigned int* gas_p;
typedef __attribute__((address_space(3))) unsigned int* las_p;

__device__ __forceinline__ void gl_lds16(const void* g, void* l) {
    __builtin_amdgcn_global_load_lds((gas_p)g, (las_p)l, 16, 0, 0);
}

__device__ __forceinline__ f32x4 mfma16(short8 a, short8 b, f32x4 c) {
    return __builtin_amdgcn_mfma_f32_16x16x32_bf16(a, b, c, 0, 0, 0);
}

__device__ __forceinline__ f32x16 mfma32(short8 a, short8 b, f32x16 c) {
    return __builtin_amdgcn_mfma_f32_32x32x16_bf16(a, b, c, 0, 0, 0);
}

__device__ __forceinline__ unsigned short f2bf(float f) {
    union { float f; unsigned int u; } v; v.f = f;
    unsigned int r = v.u + 0x7fffu + ((v.u >> 16) & 1u);
    return (unsigned short)(r >> 16);
}

__device__ __forceinline__ unsigned int cvtpk(float lo, float hi) {
    unsigned int r;
    asm("v_cvt_pk_bf16_f32 %0, %1, %2" : "=v"(r) : "v"(lo), "v"(hi));
    return r;
}
__device__ __forceinline__ void plswap(unsigned int& a, unsigned int& b) {
    asm("v_permlane32_swap_b32 %0, %1" : "+v"(a), "+v"(b));
}

// ---------------- LayerNorm: fp32 row -> bf16 normalized row ----------------
__global__ __launch_bounds__(256) void ln_kernel(const float* __restrict__ x,
                                                 const float* __restrict__ gamma,
                                                 const float* __restrict__ beta,
                                                 unsigned short* __restrict__ xn) {
    int row = blockIdx.x;
    int tid = threadIdx.x;
    const float4* xr = (const float4*)(x + (size_t)row * D_MODEL);
    float4 v = xr[tid];
    float s  = v.x + v.y + v.z + v.w;
    float ss = v.x * v.x + v.y * v.y + v.z * v.z + v.w * v.w;
    for (int off = 32; off > 0; off >>= 1) {
        s  += __shfl_down(s, off, 64);
        ss += __shfl_down(ss, off, 64);
    }
    __shared__ float red[8];
    int wid = tid >> 6;
    if ((tid & 63) == 0) { red[wid] = s; red[wid + 4] = ss; }
    __syncthreads();
    float st  = red[0] + red[1] + red[2] + red[3];
    float sst = red[4] + red[5] + red[6] + red[7];
    float mu  = st * (1.0f / D_MODEL);
    float var = sst * (1.0f / D_MODEL) - mu * mu;
    float rs  = rsqrtf(var + 1e-5f);
    const float4* g4 = (const float4*)gamma;
    const float4* b4 = (const float4*)beta;
    float4 g = g4[tid], b = b4[tid];
    ushort4 o;
    o.x = f2bf((v.x - mu) * rs * g.x + b.x);
    o.y = f2bf((v.y - mu) * rs * g.y + b.y);
    o.z = f2bf((v.z - mu) * rs * g.z + b.z);
    o.w = f2bf((v.w - mu) * rs * g.w + b.w);
    *(ushort4*)(xn + (size_t)row * D_MODEL + tid * 4) = o;
}

// -------- merged weight prep: 4x transpose+cast fp32[K][N]->bf16[N][K], + bias concat --------
// grid (32,32,4): z selects {Wq,Wk,Wv,Wo}; block(0,0,3) also writes biascat.
__global__ __launch_bounds__(256) void prep_weights(const float* __restrict__ Wq,
                                                    const float* __restrict__ Wk,
                                                    const float* __restrict__ Wv,
                                                    const float* __restrict__ Wo,
                                                    const float* __restrict__ bq,
                                                    const float* __restrict__ bk,
                                                    const float* __restrict__ bv,
                                                    unsigned short* __restrict__ wqkv_t,
                                                    unsigned short* __restrict__ wo_t,
                                                    float* __restrict__ biascat) {
    __shared__ unsigned short tile[32][33];
    int z = blockIdx.z;
    const float* src = (z == 0) ? Wq : (z == 1) ? Wk : (z == 2) ? Wv : Wo;
    unsigned short* dst = (z == 0) ? wqkv_t
                        : (z == 1) ? wqkv_t + 1024 * 1024
                        : (z == 2) ? wqkv_t + 2 * 1024 * 1024
                                   : wo_t;
    int n0 = blockIdx.x * 32;
    int k0 = blockIdx.y * 32;
    int tx = threadIdx.x;   // 0..31
    int ty = threadIdx.y;   // 0..7
    for (int i = 0; i < 4; i++) {
        int k = k0 + ty + i * 8;
        tile[ty + i * 8][tx] = f2bf(src[(size_t)k * 1024 + n0 + tx]);
    }
    __syncthreads();
    for (int i = 0; i < 4; i++) {
        int n = n0 + ty + i * 8;
        dst[(size_t)n * 1024 + k0 + tx] = tile[tx][ty + i * 8];
    }
    if (z == 3 && blockIdx.x == 0 && blockIdx.y == 0) {
        int tid = ty * 32 + tx;
        for (int i = tid; i < N_QKV; i += 256)
            biascat[i] = (i < 1024) ? bq[i] : (i < 2048 ? bk[i - 1024] : bv[i - 2048]);
    }
}

// -------- V transpose: qkv [M][3072] V-part -> vt [bh][d][s] bf16 --------
__global__ __launch_bounds__(256) void transpose_v(const unsigned short* __restrict__ qkv,
                                                   unsigned short* __restrict__ vt) {
    __shared__ __align__(16) unsigned short tile[64 * 72];
    int s0 = blockIdx.x * 64;
    int bh = blockIdx.y;
    int b = bh >> 4, h = bh & 15;
    int tid = threadIdx.x;
    const unsigned short* src = qkv + (size_t)(b * SEQ + s0) * N_QKV + 2048 + h * DK;
    for (int it = 0; it < 2; it++) {
        int o = tid + it * 256;          // 0..511
        int sl = o >> 3, ck = o & 7;     // s-local row, chunk of 8 elems
        short8 v = *(const short8*)(src + (size_t)sl * N_QKV + ck * 8);
        *(short8*)&tile[sl * 72 + ((ck ^ ((sl >> 3) & 7)) * 8)] = v;
    }
    __syncthreads();
    unsigned short* dst = vt + (size_t)bh * DK * SEQ + s0;
    for (int it = 0; it < 2; it++) {
        int o = tid + it * 256;
        int d = o >> 3, sc = (o & 7) * 8;
        short8 v;
        for (int i = 0; i < 8; i++)
            ((unsigned short*)&v)[i] =
                tile[(sc + i) * 72 + (((d >> 3) ^ (o & 7)) * 8) + (d & 7)];
        *(short8*)(dst + (size_t)d * SEQ + sc) = v;
    }
}

// -------- GEMM: m97 structure + T4 counted-vmcnt double-buffer + T1 XCD swizzle --------
// Loads for tile t+1 stay in flight across the barrier (raw s_barrier + vmcnt(4)),
// overlapping HBM latency with tile-t MFMA. Grids must be multiples of 8 blocks.
// MODE 0: bf16 out + bias (+QSCALE on Q cols). MODE 1: fp32 out + bias + residual.
template <int MODE>
__global__ __launch_bounds__(256) void gemm128(const unsigned short* __restrict__ A,
                                               const unsigned short* __restrict__ Bt,
                                               const float* __restrict__ bias,
                                               const float* __restrict__ residual,
                                               void* __restrict__ Cout,
                                               int M, int N, int K) {
    constexpr int BM = 128, BN = 128, BK = 32;
    __shared__ __align__(16) unsigned short As[2][BM * BK];
    __shared__ __align__(16) unsigned short Bs[2][BN * BK];
    // T1: bijective XCD swizzle (nwg % 8 == 0 by construction)
    int nbx = gridDim.x;
    int nwg = nbx * gridDim.y;
    int orig = blockIdx.y * nbx + blockIdx.x;
    int qq_ = nwg >> 3;
    int wg = (orig & 7) * qq_ + (orig >> 3);
    int m0 = (wg / nbx) * BM;
    int n0 = (wg % nbx) * BN;

    int tid = threadIdx.x;
    int wave = tid >> 6, lane = tid & 63;
    int wm = wave >> 1, wn = wave & 1;
    f32x4 acc[4][4] = {};

    int srow = wave * 32 + (lane >> 2);
    int scol = (lane & 3) * 8;
    const unsigned short* Ag0 = A + (size_t)(m0 + srow) * K + scol;
    const unsigned short* Ag1 = A + (size_t)(m0 + srow + 16) * K + scol;
    const unsigned short* Bg0 = Bt + (size_t)(n0 + srow) * K + scol;
    const unsigned short* Bg1 = Bt + (size_t)(n0 + srow + 16) * K + scol;

    int fr = lane & 15;
    int fq = lane >> 4;
    const int T = K / BK;

    // prologue: stage tile 0 -> buffer 0
    gl_lds16(Ag0, &As[0][(wave * 32) * BK]);
    gl_lds16(Ag1, &As[0][(wave * 32 + 16) * BK]);
    gl_lds16(Bg0, &Bs[0][(wave * 32) * BK]);
    gl_lds16(Bg1, &Bs[0][(wave * 32 + 16) * BK]);

    for (int t = 0; t < T; t++) {
        int cur = t & 1;
        if (t + 1 < T) {
            int nk = (t + 1) * BK;
            gl_lds16(Ag0 + nk, &As[cur ^ 1][(wave * 32) * BK]);
            gl_lds16(Ag1 + nk, &As[cur ^ 1][(wave * 32 + 16) * BK]);
            gl_lds16(Bg0 + nk, &Bs[cur ^ 1][(wave * 32) * BK]);
            gl_lds16(Bg1 + nk, &Bs[cur ^ 1][(wave * 32 + 16) * BK]);
            // wait oldest 4 (tile t); leave tile t+1's 4 in flight
            asm volatile("s_waitcnt vmcnt(4)" ::: "memory");
        } else {
            asm volatile("s_waitcnt vmcnt(0)" ::: "memory");
        }
        asm volatile("s_barrier" ::: "memory");   // tile t resident for all waves
        short8 a[4], b[4];
        for (int ms = 0; ms < 4; ms++)
            a[ms] = *(short8*)&As[cur][(wm * 64 + ms * 16 + fr) * BK + fq * 8];
        for (int ns = 0; ns < 4; ns++)
            b[ns] = *(short8*)&Bs[cur][(wn * 64 + ns * 16 + fr) * BK + fq * 8];
        for (int ms = 0; ms < 4; ms++)
            for (int ns = 0; ns < 4; ns++)
                acc[ms][ns] = mfma16(a[ms], b[ns], acc[ms][ns]);
        asm volatile("s_barrier" ::: "memory");   // reads done; buf[cur] reusable at t+2
    }
    for (int ms = 0; ms < 4; ms++)
        for (int ns = 0; ns < 4; ns++)
            for (int i = 0; i < 4; i++) {
                int r = m0 + wm * 64 + ms * 16 + fq * 4 + i;
                int c = n0 + wn * 64 + ns * 16 + fr;
                float val = acc[ms][ns][i] + bias[c];
                if (MODE == 0) {
                    if (c < D_MODEL) val *= QSCALE;   // Q pre-scale (exp2 domain)
                    ((unsigned short*)Cout)[(size_t)r * N + c] = f2bf(val);
                } else {
                    ((float*)Cout)[(size_t)r * N + c] = val + residual[(size_t)r * N + c];
                }
            }
}

// -------- causal flash attention, swapped-QK^T 32x32, 4-wave/128-row strips --------
// (unchanged from R6 — measured 169 -> <81 us; untouched for attribution)
__global__ __launch_bounds__(256, 4) void attn_kernel(const unsigned short* __restrict__ qkv,
                                                      const unsigned short* __restrict__ vt,
                                                      unsigned short* __restrict__ attn_out) {
    __shared__ __align__(16) unsigned short Ks[2][64 * 64];
    __shared__ __align__(16) unsigned short Vs[2][64 * 64];
    constexpr int NSTRIP = SEQ / 128;                 // 16
    int n = blockIdx.x;
    int qs = NSTRIP - 1 - (n >> 6);                   // LPT: long strips first
    int bh = n & 63;
    int b = bh >> 4, h = bh & 15;
    int tid = threadIdx.x, w = tid >> 6, lane = tid & 63;
    int l5 = lane >> 5;
    int q31 = lane & 31;
    int l7 = lane & 7;
    int S0 = qs * 128;
    int qg = S0 + w * 32 + q31;                       // this lane's global q row
    int jmax = 2 * qs + 1;                            // kv tiles 0..jmax
    int jd = 2 * qs + (w >> 1);                       // wave's diagonal tile

    const unsigned short* kbase = qkv + (size_t)(b * SEQ) * N_QKV + D_MODEL + h * DK;
    const unsigned short* vtb = vt + (size_t)bh * DK * SEQ;

    const unsigned short* qptr = qkv + (size_t)(b * SEQ + qg) * N_QKV + h * DK;
    short8 qf[4];
#pragma unroll
    for (int s = 0; s < 4; s++)
        qf[s] = *(const short8*)(qptr + 16 * s + 8 * l5);

    int srow = lane >> 3;                  // 0..7 within 8-row group
    int schunk = (l7 ^ srow) * 8;          // pre-swizzled global chunk (m173)

    f32x16 ot0 = {}, ot1 = {};
    float mold = -1e30f, lsum = 0.f;

#pragma unroll
    for (int c = 0; c < 2; c++) {
        int rl_ = w * 16 + c * 8;
        gl_lds16(kbase + (size_t)(rl_ + srow) * N_QKV + schunk, &Ks[0][rl_ * 64]);
        gl_lds16(vtb + (size_t)(rl_ + srow) * SEQ + schunk, &Vs[0][rl_ * 64]);
    }
    __syncthreads();

    for (int j = 0; j <= jmax; j++) {
        int bb = j & 1;
        if (j < jmax) {
#pragma unroll
            for (int c = 0; c < 2; c++) {
                int rl_ = w * 16 + c * 8;
                gl_lds16(kbase + (size_t)((j + 1) * 64 + rl_ + srow) * N_QKV + schunk,
                         &Ks[bb ^ 1][rl_ * 64]);
                gl_lds16(vtb + (size_t)(rl_ + srow) * SEQ + (j + 1) * 64 + schunk,
                         &Vs[bb ^ 1][rl_ * 64]);
            }
        }
        if (j <= jd) {   // tiles beyond the wave's diagonal are fully masked: skip
            const unsigned short* kb = Ks[bb];
            const unsigned short* vb = Vs[bb];
            f32x16 s0 = {}, s1 = {};
            __builtin_amdgcn_s_setprio(1);
#pragma unroll
            for (int s = 0; s < 4; s++) {
                int co = (((s << 1) | l5) ^ l7) * 8;
                short8 k0 = *(const short8*)&kb[(q31) * 64 + co];
                short8 k1 = *(const short8*)&kb[(32 + q31) * 64 + co];
                s0 = mfma32(k0, qf[s], s0);
                s1 = mfma32(k1, qf[s], s1);
            }
            __builtin_amdgcn_s_setprio(0);
            if (j == jd) {
#pragma unroll
                for (int r = 0; r < 16; r++) {
                    int kv0 = j * 64 + (r & 3) + 8 * (r >> 2) + 4 * l5;
                    if (kv0 > qg) s0[r] = -1e30f;
                    if (kv0 + 32 > qg) s1[r] = -1e30f;
                }
            }
            float tm[16];
#pragma unroll
            for (int r = 0; r < 16; r++) tm[r] = fmaxf(s0[r], s1[r]);
#pragma unroll
            for (int st = 8; st > 0; st >>= 1)
#pragma unroll
                for (int r = 0; r < 8; r++)
                    if (r < st) tm[r] = fmaxf(tm[r], tm[r + st]);
            float mloc = fmaxf(tm[0], __shfl_xor(tm[0], 32));
            if (!__all(mloc - mold <= 11.0f)) {
                float mnew = fmaxf(mold, mloc);
                float aexp = exp2f(mold - mnew);
                lsum *= aexp;
#pragma unroll
                for (int r = 0; r < 16; r++) { ot0[r] *= aexp; ot1[r] *= aexp; }
                mold = mnew;
            }
            float ts[16];
#pragma unroll
            for (int r = 0; r < 16; r++) {
                s0[r] = exp2f(s0[r] - mold);
                s1[r] = exp2f(s1[r] - mold);
                ts[r] = s0[r] + s1[r];
            }
#pragma unroll
            for (int st = 8; st > 0; st >>= 1)
#pragma unroll
                for (int r = 0; r < 8; r++)
                    if (r < st) ts[r] += ts[r + st];
            lsum += ts[0] + __shfl_xor(ts[0], 32);

            union { unsigned int wd[4]; short8 v; } pf;
#pragma unroll
            for (int t = 0; t < 4; t++) {
                int b2 = t & 1;
                unsigned int pa, pb, pc, pd;
                if (t < 2) {
                    pa = cvtpk(s0[8 * b2 + 0], s0[8 * b2 + 1]);
                    pb = cvtpk(s0[8 * b2 + 2], s0[8 * b2 + 3]);
                    pc = cvtpk(s0[8 * b2 + 4], s0[8 * b2 + 5]);
                    pd = cvtpk(s0[8 * b2 + 6], s0[8 * b2 + 7]);
                } else {
                    pa = cvtpk(s1[8 * b2 + 0], s1[8 * b2 + 1]);
                    pb = cvtpk(s1[8 * b2 + 2], s1[8 * b2 + 3]);
                    pc = cvtpk(s1[8 * b2 + 4], s1[8 * b2 + 5]);
                    pd = cvtpk(s1[8 * b2 + 6], s1[8 * b2 + 7]);
                }
                plswap(pa, pc);
                plswap(pb, pd);
                pf.wd[0] = pa; pf.wd[1] = pb; pf.wd[2] = pc; pf.wd[3] = pd;
                int co = (((t << 1) | l5) ^ l7) * 8;
                short8 v0 = *(const short8*)&vb[(q31) * 64 + co];
                short8 v1 = *(const short8*)&vb[(32 + q31) * 64 + co];
                __builtin_amdgcn_s_setprio(1);
                ot0 = mfma32(v0, pf.v, ot0);
                ot1 = mfma32(v1, pf.v, ot1);
                __builtin_amdgcn_s_setprio(0);
            }
        }
        __syncthreads();   // drains staging loads, releases buffers
    }

    float rl = 1.0f / lsum;
    unsigned short* ob = attn_out + (size_t)(b * SEQ + qg) * D_MODEL + h * DK + 4 * l5;
#pragma unroll
    for (int qq = 0; qq < 4; qq++) {
        uint2 val;
        val.x = cvtpk(ot0[4 * qq + 0] * rl, ot0[4 * qq + 1] * rl);
        val.y = cvtpk(ot0[4 * qq + 2] * rl, ot0[4 * qq + 3] * rl);
        *(uint2*)(ob + 8 * qq) = val;
        val.x = cvtpk(ot1[4 * qq + 0] * rl, ot1[4 * qq + 1] * rl);
        val.y = cvtpk(ot1[4 * qq + 2] * rl, ot1[4 * qq + 3] * rl);
        *(uint2*)(ob + 32 + 8 * qq) = val;
    }
}

extern "C" void kernel_launch(void* const* d_in, const int* in_sizes, int n_in,
                              void* d_out, int out_size, void* d_ws, size_t ws_size,
                              hipStream_t stream) {
    const float* x     = (const float*)d_in[0];
    const float* Wq    = (const float*)d_in[1];
    const float* bq    = (const float*)d_in[2];
    const float* Wk    = (const float*)d_in[3];
    const float* bk    = (const float*)d_in[4];
    const float* Wv    = (const float*)d_in[5];
    const float* bv    = (const float*)d_in[6];
    const float* Wo    = (const float*)d_in[7];
    const float* bo    = (const float*)d_in[8];
    const float* gamma = (const float*)d_in[9];
    const float* beta  = (const float*)d_in[10];
    float* out = (float*)d_out;

    char* ws = (char*)d_ws;
    unsigned short* xn     = (unsigned short*)ws;                      // 16 MB (dead after QKV gemm)
    unsigned short* aout   = xn;                                       // alias
    unsigned short* wqkv_t = (unsigned short*)(ws + (16u << 20));      // 6 MB
    unsigned short* wo_t   = (unsigned short*)(ws + (22u << 20));      // 2 MB
    unsigned short* qkv    = (unsigned short*)(ws + (24u << 20));      // 48 MB
    unsigned short* vt     = (unsigned short*)(ws + (72u << 20));      // 16 MB
    float* biascat         = (float*)(ws + (88u << 20));               // 12 KB

    ln_kernel<<<M_TOTAL, 256, 0, stream>>>(x, gamma, beta, xn);
    prep_weights<<<dim3(32, 32, 4), dim3(32, 8), 0, stream>>>(
        Wq, Wk, Wv, Wo, bq, bk, bv, wqkv_t, wo_t, biascat);

    gemm128<0><<<dim3(N_QKV / 128, M_TOTAL / 128), 256, 0, stream>>>(
        xn, wqkv_t, biascat, nullptr, qkv, M_TOTAL, N_QKV, D_MODEL);

    transpose_v<<<dim3(SEQ / 64, BATCH * NHEADS), 256, 0, stream>>>(qkv, vt);

    attn_kernel<<<dim3((SEQ / 128) * BATCH * NHEADS), 256, 0, stream>>>(qkv, vt, aout);

    gemm128<1><<<dim3(D_MODEL / 128, M_TOTAL / 128), 256, 0, stream>>>(
        aout, wo_t, bo, x, out, M_TOTAL, D_MODEL, D_MODEL);
}